// Round 10
// baseline (1448.343 us; speedup 1.0000x reference)
//
#include <hip/hip_runtime.h>
#include <hip/hip_bf16.h>

// ---------------------------------------------------------------------------
// Transformer decoder, fp32 I/O, split-bf16 MFMA everywhere.
// R10: R8 tiles (64^2) + deeper K-splits via fp32 partials (QKV z=6, merged
// Qc+KVc z=6, O-proj z=4) + lean combine kernels + merged embed/cvt.
// B=2, ST=SS=1024, D=512, H=8, DK=64, L=4, DFF=2048, V=32000.
// ---------------------------------------------------------------------------

#define D_MODEL 512
#define NHEAD   8
#define DKH     64
#define SEQ     1024
#define NLAYER  4
#define DFF_    2048
#define VOCAB   32000
#define BATCH   2
#define MROWS   (BATCH*SEQ)   // 2048
#define PSLAB   1048576L

typedef short bf16x8 __attribute__((ext_vector_type(8)));
typedef short short4v __attribute__((ext_vector_type(4)));
typedef float f32x4  __attribute__((ext_vector_type(4)));

static __device__ __forceinline__ short f2bf(float f) {
    __hip_bfloat16 h = __float2bfloat16(f);
    return *reinterpret_cast<short*>(&h);
}
static __device__ __forceinline__ float bf2f(short s) {
    __hip_bfloat16 h = *reinterpret_cast<__hip_bfloat16*>(&s);
    return __bfloat162float(h);
}
static __device__ __forceinline__ void gld16(const void* g, void* l) {
    __builtin_amdgcn_global_load_lds(
        (__attribute__((address_space(1))) void*)(void*)g,
        (__attribute__((address_space(3))) void*)l, 16, 0, 0);
}

// ---------------- embedding+PE (blocks 0..4095) | enc cvt (4096..5119) ------
__global__ __launch_bounds__(256) void embed_cvt_kernel(
    const int* __restrict__ tokens, const float* __restrict__ emb,
    float* __restrict__ x, short* __restrict__ xh, short* __restrict__ xl,
    const float* __restrict__ enc, short* __restrict__ ench, short* __restrict__ encl)
{
    if (blockIdx.x < 4096) {
        long idx = (long)blockIdx.x * 256 + threadIdx.x;   // over 1,048,576
        int  d   = (int)(idx & (D_MODEL - 1));
        long row = idx >> 9;
        int  s   = (int)(row & (SEQ - 1));
        int  tok = tokens[row];
        float twoi = (float)((d >> 1) << 1);
        float div  = expf(twoi * (-9.210340371976184f / 512.0f));
        float arg  = (float)s * div;
        float pe   = (d & 1) ? cosf(arg) : sinf(arg);
        float v = emb[(long)tok * D_MODEL + d] * 22.62741699796952f + pe;
        x[idx] = v;
        short h = f2bf(v);
        xh[idx] = h;
        xl[idx] = f2bf(v - bf2f(h));
    } else {
        long e = ((long)(blockIdx.x - 4096) * 256 + threadIdx.x) * 4;
        float4 v = *(const float4*)&enc[e];
        float f[4] = {v.x, v.y, v.z, v.w};
#pragma unroll
        for (int i = 0; i < 4; ++i) {
            short hh = f2bf(f[i]);
            ench[e + i] = hh;
            encl[e + i] = f2bf(f[i] - bf2f(hh));
        }
    }
}

// ---------------- weight transpose-convert: W[K,N] -> WT[N,K] hi/lo ---------
__global__ __launch_bounds__(256) void wtrans_kernel(
    const float* __restrict__ W, short* __restrict__ Th, short* __restrict__ Tl,
    int K, int ldW)
{
    const int n0 = blockIdx.x * 64, k0 = blockIdx.y * 64;
    __shared__ float tile[64][65];
    const int t = threadIdx.x;
#pragma unroll
    for (int i = 0; i < 4; ++i) {
        int e = t + i * 256; int kk = e >> 4; int nn = (e & 15) * 4;
        float4 v = *(const float4*)&W[(long)(k0 + kk) * ldW + n0 + nn];
        tile[kk][nn] = v.x; tile[kk][nn + 1] = v.y;
        tile[kk][nn + 2] = v.z; tile[kk][nn + 3] = v.w;
    }
    __syncthreads();
    const int n = t >> 2, ks = (t & 3) * 16;
    short h8[16], l8[16];
#pragma unroll
    for (int j = 0; j < 16; ++j) {
        float f = tile[ks + j][n];
        short h = f2bf(f);
        h8[j] = h;
        l8[j] = f2bf(f - bf2f(h));
    }
    long base = (long)(n0 + n) * K + k0 + ks;
    *(bf16x8*)&Th[base]     = *(bf16x8*)&h8[0];
    *(bf16x8*)&Th[base + 8] = *(bf16x8*)&h8[8];
    *(bf16x8*)&Tl[base]     = *(bf16x8*)&l8[0];
    *(bf16x8*)&Tl[base + 8] = *(bf16x8*)&l8[8];
}

// ---------------- merged per-layer weight transpose (10 matrices) -----------
__global__ __launch_bounds__(256) void wtrans_layer_kernel(
    const float* __restrict__ Wqkvo, const float* __restrict__ W1,
    const float* __restrict__ W2, int l,
    short* __restrict__ Th, short* __restrict__ Tl)
{
    const int j = blockIdx.x;
    const float* W; int ldW, K; long dstOff; int n0, k0;
    if (j < 512) {
        int mat = j >> 6, tile_ = j & 63;
        W = Wqkvo + (long)l * 2097152L + (long)mat * 262144L;
        ldW = 512; K = 512; dstOff = (long)mat * 262144L;
        n0 = (tile_ & 7) * 64; k0 = (tile_ >> 3) * 64;
    } else if (j < 768) {
        int t2 = j - 512;
        W = W1 + (long)l * 1048576L; ldW = 2048; K = 512; dstOff = 2097152L;
        n0 = (t2 & 31) * 64; k0 = (t2 >> 5) * 64;
    } else {
        int t3 = j - 768;
        W = W2 + (long)l * 1048576L; ldW = 512; K = 2048; dstOff = 3145728L;
        n0 = (t3 & 7) * 64; k0 = (t3 >> 3) * 64;
    }
    __shared__ float tile[64][65];
    const int t = threadIdx.x;
#pragma unroll
    for (int i = 0; i < 4; ++i) {
        int e = t + i * 256; int kk = e >> 4; int nn = (e & 15) * 4;
        float4 v = *(const float4*)&W[(long)(k0 + kk) * ldW + n0 + nn];
        tile[kk][nn] = v.x; tile[kk][nn + 1] = v.y;
        tile[kk][nn + 2] = v.z; tile[kk][nn + 3] = v.w;
    }
    __syncthreads();
    const int n = t >> 2, ks = (t & 3) * 16;
    short h8[16], l8[16];
#pragma unroll
    for (int j2 = 0; j2 < 16; ++j2) {
        float f = tile[ks + j2][n];
        short h = f2bf(f);
        h8[j2] = h;
        l8[j2] = f2bf(f - bf2f(h));
    }
    long base = dstOff + (long)(n0 + n) * K + k0 + ks;
    *(bf16x8*)&Th[base]     = *(bf16x8*)&h8[0];
    *(bf16x8*)&Th[base + 8] = *(bf16x8*)&h8[8];
    *(bf16x8*)&Tl[base]     = *(bf16x8*)&l8[0];
    *(bf16x8*)&Tl[base + 8] = *(bf16x8*)&l8[8];
}

// ---------------- split-bf16 MFMA GEMM (64^2 or 128^2 tile) -----------------
// MODE 0: fp32+bias. MODE 2: bf16 hi/lo+bias(+relu). MODE 5: fp32 partial,
// no bias, K-window z*kOff. MODE 6: fp32 partial, z=(mat,khalf): B += (z>>1)*zB,
// K-window (z&1)*kOff, A switches to A2 at z>=aSwitchZ.
template<int BT, int ACT, int MODE>
__global__ __launch_bounds__(256) void gemm_mfma_kernel(
    const short* __restrict__ Ah, const short* __restrict__ Al,
    const short* __restrict__ A2h, const short* __restrict__ A2l,
    const short* __restrict__ Bh, const short* __restrict__ Bl,
    const float* __restrict__ bias, float* __restrict__ C,
    short* __restrict__ Ch, short* __restrict__ Cl,
    int Keff, int ldA, int ldB, int ldc,
    long zB, long zBias, long zC, int kOff, int aSwitchZ)
{
    constexpr int HM = BT / 2;
    constexpr int MT = BT / 32;
    const long z = blockIdx.z;
    if (MODE == 6) { Bh += (z >> 1) * zB; Bl += (z >> 1) * zB; }
    else           { Bh += z * zB;        Bl += z * zB; }
    if (MODE != 5 && MODE != 6) bias += z * zBias;

    const short* Au = (MODE == 6 && (int)z >= aSwitchZ) ? A2h : Ah;
    const short* Av = (MODE == 6 && (int)z >= aSwitchZ) ? A2l : Al;

    const int n0 = blockIdx.x * BT, m0 = blockIdx.y * BT;
    const int t = threadIdx.x;
    const int w = t >> 6, lane = t & 63;
    const int wm = w >> 1, wn = w & 1;
    const int lr = lane & 15, ks = lane >> 4;

    __shared__ short sAh[BT * 32], sAl[BT * 32], sBh[BT * 32], sBl[BT * 32];

    f32x4 acc[MT][MT];
#pragma unroll
    for (int i = 0; i < MT; ++i)
#pragma unroll
        for (int j = 0; j < MT; ++j) acc[i][j] = (f32x4){0.f, 0.f, 0.f, 0.f};

    const int kwin = (MODE == 6) ? (int)(z & 1) * kOff : (int)z * kOff;
    const long rowA = ((long)m0 * ldA + kwin) * 2;   // bytes
    const long rowB = ((long)n0 * ldB + kwin) * 2;

    for (int k0 = 0; k0 < Keff; k0 += 32) {
#pragma unroll
        for (int i = 0; i < BT / 64; ++i) {
            const int  L = i * 4096 + t * 16;
            const int  r = L >> 6, s = L & 63;
            const long gbA = ((long)r * ldA + k0) * 2 + s;
            const long gbB = ((long)r * ldB + k0) * 2 + s;
            gld16((const char*)Au + rowA + gbA, (char*)sAh + L);
            gld16((const char*)Av + rowA + gbA, (char*)sAl + L);
            gld16((const char*)Bh + rowB + gbB, (char*)sBh + L);
            gld16((const char*)Bl + rowB + gbB, (char*)sBl + L);
        }
        __syncthreads();

        bf16x8 ah[MT], al[MT], bh[MT], bl[MT];
#pragma unroll
        for (int mt = 0; mt < MT; ++mt) {
            int row = wm * HM + mt * 16 + lr;
            ah[mt] = *(const bf16x8*)&sAh[row * 32 + ks * 8];
            al[mt] = *(const bf16x8*)&sAl[row * 32 + ks * 8];
            int col = wn * HM + mt * 16 + lr;
            bh[mt] = *(const bf16x8*)&sBh[col * 32 + ks * 8];
            bl[mt] = *(const bf16x8*)&sBl[col * 32 + ks * 8];
        }
#pragma unroll
        for (int mt = 0; mt < MT; ++mt)
#pragma unroll
            for (int nt = 0; nt < MT; ++nt) {
                acc[mt][nt] = __builtin_amdgcn_mfma_f32_16x16x32_bf16(
                    ah[mt], bh[nt], acc[mt][nt], 0, 0, 0);
                acc[mt][nt] = __builtin_amdgcn_mfma_f32_16x16x32_bf16(
                    ah[mt], bl[nt], acc[mt][nt], 0, 0, 0);
                acc[mt][nt] = __builtin_amdgcn_mfma_f32_16x16x32_bf16(
                    al[mt], bh[nt], acc[mt][nt], 0, 0, 0);
            }
        __syncthreads();
    }

    const int rq = lane >> 4, cq = lane & 15;
#pragma unroll
    for (int mt = 0; mt < MT; ++mt)
#pragma unroll
        for (int nt = 0; nt < MT; ++nt) {
            int gr0 = m0 + wm * HM + mt * 16 + rq * 4;
            int gc  = n0 + wn * HM + nt * 16 + cq;
            float bv = (MODE == 5 || MODE == 6) ? 0.f : bias[gc];
#pragma unroll
            for (int i = 0; i < 4; ++i) {
                float v = acc[mt][nt][i] + bv;
                if (ACT == 1) v = fmaxf(v, 0.f);
                if (MODE == 0 || MODE == 5 || MODE == 6) {
                    C[(long)(gr0 + i) * ldc + gc + z * zC] = v;
                } else {    // MODE 2
                    long off = (long)(gr0 + i) * ldc + gc;
                    short h = f2bf(v);
                    Ch[off] = h;
                    Cl[off] = f2bf(v - bf2f(h));
                }
            }
        }
}

// ---------------- combine: 6 partial slabs -> Q(scaled,swz), K(swz), VT -----
// part layout: slab (mat*2 + khalf); mat 0=Q(*0.125), 1=K, 2=V(transposed out).
__global__ __launch_bounds__(256) void qkv_combine_kernel(
    const float* __restrict__ part, const float* __restrict__ bias,
    short* __restrict__ Qh, short* __restrict__ Ql,
    short* __restrict__ Kh, short* __restrict__ Kl,
    short* __restrict__ VTh, short* __restrict__ VTl)
{
    long tid = (long)blockIdx.x * 256 + threadIdx.x;   // 786432 threads
    int mat = (int)(tid >> 18);
    int rem = (int)(tid & 262143);

    if (mat < 2) {
        int gr = rem >> 7;
        int gc4 = (rem & 127) * 4;
        const float* p0 = part + (long)(mat * 2) * PSLAB + (long)gr * 512 + gc4;
        float4 a = *(const float4*)p0;
        float4 b2 = *(const float4*)(p0 + PSLAB);
        float4 bv = *(const float4*)&bias[mat * 512 + gc4];
        float sc = (mat == 0) ? 0.125f : 1.f;
        float v[4] = {(a.x + b2.x + bv.x) * sc, (a.y + b2.y + bv.y) * sc,
                      (a.z + b2.z + bv.z) * sc, (a.w + b2.w + bv.w) * sc};
        int b = gr >> 10, s = gr & (SEQ - 1);
        int hh = gc4 >> 6, dk4 = gc4 & 63;
        int dks = dk4 ^ (((s >> 1) & 7) << 3);
        long o = (((long)(b * NHEAD + hh)) * SEQ + s) * 64 + dks;
        short4v hv, lv;
#pragma unroll
        for (int i = 0; i < 4; ++i) {
            short h = f2bf(v[i]);
            hv[i] = h;
            lv[i] = f2bf(v[i] - bf2f(h));
        }
        short* oh = (mat == 0) ? Qh : Kh;
        short* ol = (mat == 0) ? Ql : Kl;
        *(short4v*)&oh[o] = hv;
        *(short4v*)&ol[o] = lv;
    } else {
        // V: thread owns 4 consecutive rows (s) at one column gc -> VT column write
        int gc = rem & 511;
        int gr4 = (rem >> 9) << 2;
        const float* p0 = part + 4L * PSLAB;
        float bv = bias[2 * 512 + gc];
        int b = gr4 >> 10, s0 = gr4 & (SEQ - 1);
        int hh = gc >> 6, dk = gc & 63;
        int swz = (((dk >> 1) & 3) << 3) | (((dk >> 3) & 1) << 5);
        long base = (((long)(b * NHEAD + hh)) * 64 + dk) * 1024
                  + (long)(((s0 & ~7) ^ swz) | (s0 & 7));
        short4v hv, lv;
#pragma unroll
        for (int i = 0; i < 4; ++i) {
            long ri = (long)(gr4 + i) * 512 + gc;
            float v = p0[ri] + p0[ri + PSLAB] + bv;
            short h = f2bf(v);
            hv[i] = h;
            lv[i] = f2bf(v - bf2f(h));
        }
        *(short4v*)&VTh[base] = hv;
        *(short4v*)&VTl[base] = lv;
    }
}

// ---------------- fused attention: 32 q-rows, 2 waves, 2 blocks/CU ----------
template<bool CAUSAL>
__global__ __launch_bounds__(128) void attn_fused_kernel(
    const short* __restrict__ Qh, const short* __restrict__ Ql,
    const short* __restrict__ Kh, const short* __restrict__ Kl,
    const short* __restrict__ VTh, const short* __restrict__ VTl,
    float* __restrict__ attn, short* __restrict__ Oh, short* __restrict__ Ol)
{
    const int strip = blockIdx.x, bh = blockIdx.y;
    const int q0 = strip * 32;
    const int t = threadIdx.x, w = t >> 6, lane = t & 63;
    const int lr = lane & 15, ks = lane >> 4;
    const int rq = lane >> 4, cq = lane & 15;
    const int sxq = (lr >> 1) & 7;

    __shared__ short sKh[2][64*64], sKl[2][64*64];   // 32 KB
    __shared__ short sVh[2][64*64], sVl[2][64*64];   // 32 KB
    __shared__ short sPh[2][16*80], sPl[2][16*80];   // 10 KB

    const int diag  = strip >> 1;
    const int ktmax = CAUSAL ? diag + 1 : 16;

    {
        const long qb = ((long)bh * SEQ + q0) * 128;
#pragma unroll
        for (int i2 = 0; i2 < 2; ++i2) {
            int L = i2 * 2048 + t * 16; int r = L >> 7, off = L & 127;
            gld16((const char*)Qh + qb + (long)r*128 + off, (char*)&sVh[0][0] + L);
            gld16((const char*)Ql + qb + (long)r*128 + off, (char*)&sVl[0][0] + L);
        }
    }
    __syncthreads();
    bf16x8 qa[2][2];
#pragma unroll
    for (int k0 = 0; k0 < 2; ++k0) {
        int o = (w*16 + lr) * 64 + ((k0*32 + ks*8) ^ (sxq << 3));
        qa[k0][0] = *(const bf16x8*)&sVh[0][o];
        qa[k0][1] = *(const bf16x8*)&sVl[0][o];
    }
    __syncthreads();

    auto stageK = [&](int buf, int kt) {
        const long kb = ((long)bh * SEQ + kt*64) * 128;
#pragma unroll
        for (int i2 = 0; i2 < 4; ++i2) {
            int L = i2*2048 + t*16; int r = L >> 7, off = L & 127;
            gld16((const char*)Kh + kb + (long)r*128 + off, (char*)&sKh[buf][0] + L);
            gld16((const char*)Kl + kb + (long)r*128 + off, (char*)&sKl[buf][0] + L);
        }
    };
    auto stageV = [&](int buf, int kt) {
        const long vb = ((long)bh * 64) * 2048 + (long)kt * 128;
#pragma unroll
        for (int i2 = 0; i2 < 4; ++i2) {
            int L = i2*2048 + t*16; int r = L >> 7, off = L & 127;
            gld16((const char*)VTh + vb + (long)r*2048 + off, (char*)&sVh[buf][0] + L);
            gld16((const char*)VTl + vb + (long)r*2048 + off, (char*)&sVl[buf][0] + L);
        }
    };
    auto scoresOf = [&](int buf, int kt, f32x4* sc) {
#pragma unroll
        for (int nt = 0; nt < 4; ++nt) sc[nt] = (f32x4){0.f, 0.f, 0.f, 0.f};
#pragma unroll
        for (int k0 = 0; k0 < 2; ++k0) {
            bf16x8 kh[4], kl[4];
#pragma unroll
            for (int nt = 0; nt < 4; ++nt) {
                int o = (nt*16 + lr) * 64 + ((k0*32 + ks*8) ^ (sxq << 3));
                kh[nt] = *(const bf16x8*)&sKh[buf][o];
                kl[nt] = *(const bf16x8*)&sKl[buf][o];
            }
#pragma unroll
            for (int nt = 0; nt < 4; ++nt) {
                sc[nt] = __builtin_amdgcn_mfma_f32_16x16x32_bf16(
                    qa[k0][0], kh[nt], sc[nt], 0, 0, 0);
                sc[nt] = __builtin_amdgcn_mfma_f32_16x16x32_bf16(
                    qa[k0][0], kl[nt], sc[nt], 0, 0, 0);
                sc[nt] = __builtin_amdgcn_mfma_f32_16x16x32_bf16(
                    qa[k0][1], kh[nt], sc[nt], 0, 0, 0);
            }
        }
        if (CAUSAL && kt == diag) {
            int row = q0 + w*16 + rq*4;
#pragma unroll
            for (int nt = 0; nt < 4; ++nt) {
                int col = kt*64 + nt*16 + cq;
#pragma unroll
                for (int i = 0; i < 4; ++i)
                    if (col > row + i) sc[nt][i] = -1e9f;
            }
        }
    };

    // ---- pass 1: online max + sum ----
    float m[4]   = {-3e38f, -3e38f, -3e38f, -3e38f};
    float sum[4] = {0.f, 0.f, 0.f, 0.f};
    int cur = 0;
    stageK(0, 0);
    __syncthreads();
    for (int kt = 0; kt < ktmax; ++kt) {
        if (kt + 1 < ktmax) stageK(cur ^ 1, kt + 1);
        f32x4 sc[4];
        scoresOf(cur, kt, sc);
#pragma unroll
        for (int i = 0; i < 4; ++i) {
            float tm = fmaxf(fmaxf(sc[0][i], sc[1][i]), fmaxf(sc[2][i], sc[3][i]));
#pragma unroll
            for (int d2 = 1; d2 <= 8; d2 <<= 1) tm = fmaxf(tm, __shfl_xor(tm, d2, 64));
            float mn = fmaxf(m[i], tm);
            float ps = __expf(sc[0][i] - mn) + __expf(sc[1][i] - mn)
                     + __expf(sc[2][i] - mn) + __expf(sc[3][i] - mn);
#pragma unroll
            for (int d2 = 1; d2 <= 8; d2 <<= 1) ps += __shfl_xor(ps, d2, 64);
            sum[i] = sum[i] * __expf(m[i] - mn) + ps;
            m[i] = mn;
        }
        __syncthreads();
        cur ^= 1;
    }
    float inv[4];
#pragma unroll
    for (int i = 0; i < 4; ++i) inv[i] = 1.f / sum[i];

    // ---- pass 2: recompute, probs out, PV ----
    f32x4 acco[4];
#pragma unroll
    for (int nt = 0; nt < 4; ++nt) acco[nt] = (f32x4){0.f, 0.f, 0.f, 0.f};

    cur = 0;
    stageK(0, 0); stageV(0, 0);
    __syncthreads();
    for (int kt = 0; kt < 16; ++kt) {
        if (kt >= ktmax) {
#pragma unroll
            for (int nt = 0; nt < 4; ++nt)
#pragma unroll
                for (int i = 0; i < 4; ++i)
                    attn[((long)bh << 20) + ((long)(q0 + w*16 + rq*4 + i) << 10)
                         + kt*64 + nt*16 + cq] = 0.f;
            continue;
        }
        if (kt + 1 < ktmax) { stageK(cur ^ 1, kt + 1); stageV(cur ^ 1, kt + 1); }
        f32x4 sc[4];
        scoresOf(cur, kt, sc);
#pragma unroll
        for (int nt = 0; nt < 4; ++nt)
#pragma unroll
            for (int i = 0; i < 4; ++i) {
                float p = __expf(sc[nt][i] - m[i]) * inv[i];
                attn[((long)bh << 20) + ((long)(q0 + w*16 + rq*4 + i) << 10)
                     + kt*64 + nt*16 + cq] = p;
                short ph = f2bf(p);
                sPh[w][(rq*4 + i)*80 + nt*16 + cq] = ph;
                sPl[w][(rq*4 + i)*80 + nt*16 + cq] = f2bf(p - bf2f(ph));
            }
#pragma unroll
        for (int k0 = 0; k0 < 2; ++k0) {
            bf16x8 pah = *(const bf16x8*)&sPh[w][lr*80 + k0*32 + ks*8];
            bf16x8 pal = *(const bf16x8*)&sPl[w][lr*80 + k0*32 + ks*8];
#pragma unroll
            for (int nt = 0; nt < 4; ++nt) {
                int dk = nt*16 + lr;
                int swz = (((dk >> 1) & 3) << 3) | (((dk >> 3) & 1) << 5);
                int koff = (k0*32 + ks*8) ^ swz;
                bf16x8 vh8 = *(const bf16x8*)&sVh[cur][dk*64 + koff];
                bf16x8 vl8 = *(const bf16x8*)&sVl[cur][dk*64 + koff];
                acco[nt] = __builtin_amdgcn_mfma_f32_16x16x32_bf16(
                    pah, vh8, acco[nt], 0, 0, 0);
                acco[nt] = __builtin_amdgcn_mfma_f32_16x16x32_bf16(
                    pah, vl8, acco[nt], 0, 0, 0);
                acco[nt] = __builtin_amdgcn_mfma_f32_16x16x32_bf16(
                    pal, vh8, acco[nt], 0, 0, 0);
            }
        }
        __syncthreads();
        cur ^= 1;
    }

    const int b = bh >> 3, hh_ = bh & 7;
#pragma unroll
    for (int nt = 0; nt < 4; ++nt)
#pragma unroll
        for (int i = 0; i < 4; ++i) {
            float v = acco[nt][i];
            long oidx = ((long)(b * SEQ + q0 + w*16 + rq*4 + i)) * D_MODEL
                      + hh_*64 + nt*16 + cq;
            short h2 = f2bf(v);
            Oh[oidx] = h2;
            Ol[oidx] = f2bf(v - bf2f(h2));
        }
}

// ---------------- residual + NS partial slabs + bias + LayerNorm + hi/lo ----
template<int NS>
__global__ __launch_bounds__(256) void add_ln_kernel(
    const float* __restrict__ xin, const float* __restrict__ part, long PS,
    const float* __restrict__ bias,
    const float* __restrict__ g, const float* __restrict__ bb,
    float* __restrict__ xout, short* __restrict__ xh, short* __restrict__ xl)
{
    long row = blockIdx.x;
    const float* xr = xin + row * D_MODEL;
    float*       xo = xout+ row * D_MODEL;
    short*       hh = xh  + row * D_MODEL;
    short*       ll = xl  + row * D_MODEL;
    int t = threadIdx.x;

    float a0 = xr[t]       + bias[t];
    float a1 = xr[t + 256] + bias[t + 256];
#pragma unroll
    for (int s2 = 0; s2 < NS; ++s2) {
        a0 += part[s2 * PS + row * D_MODEL + t];
        a1 += part[s2 * PS + row * D_MODEL + t + 256];
    }

    float s = a0 + a1;
#pragma unroll
    for (int m = 32; m; m >>= 1) s += __shfl_xor(s, m, 64);
    __shared__ float red1[4];
    __shared__ float red2[4];
    int w = t >> 6, lane = t & 63;
    if (lane == 0) red1[w] = s;
    __syncthreads();
    float mean = (red1[0] + red1[1] + red1[2] + red1[3]) * (1.f / 512.f);

    float d0 = a0 - mean, d1 = a1 - mean;
    float q = d0 * d0 + d1 * d1;
#pragma unroll
    for (int m = 32; m; m >>= 1) q += __shfl_xor(q, m, 64);
    if (lane == 0) red2[w] = q;
    __syncthreads();
    float var  = (red2[0] + red2[1] + red2[2] + red2[3]) * (1.f / 512.f);
    float rstd = rsqrtf(var + 1e-5f);

    float r0 = d0 * rstd * g[t]       + bb[t];
    float r1 = d1 * rstd * g[t + 256] + bb[t + 256];
    xo[t] = r0; xo[t + 256] = r1;
    short h0 = f2bf(r0); hh[t] = h0;       ll[t] = f2bf(r0 - bf2f(h0));
    short h1 = f2bf(r1); hh[t + 256] = h1; ll[t + 256] = f2bf(r1 - bf2f(h1));
}

// ---------------------------------------------------------------------------
extern "C" void kernel_launch(void* const* d_in, const int* in_sizes, int n_in,
                              void* d_out, int out_size, void* d_ws, size_t ws_size,
                              hipStream_t stream)
{
    const int*   tokens = (const int*)  d_in[0];
    const float* enc    = (const float*)d_in[1];
    const float* emb    = (const float*)d_in[3];
    const float* Wqkvo  = (const float*)d_in[4];   // [L,2,4,D,D]
    const float* bqkvo  = (const float*)d_in[5];   // [L,2,4,D]
    const float* W1     = (const float*)d_in[6];   // [L,D,DFF]
    const float* b1     = (const float*)d_in[7];
    const float* W2     = (const float*)d_in[8];   // [L,DFF,D]
    const float* b2     = (const float*)d_in[9];
    const float* lng    = (const float*)d_in[10];  // [L,3,D]
    const float* lnb    = (const float*)d_in[11];
    const float* Wout   = (const float*)d_in[12];  // [D,V]
    const float* bout   = (const float*)d_in[13];

    float* out    = (float*)d_out;
    float* selfA  = out + 65536000L;
    float* crossA = selfA + 67108864L;

    // workspace carve (~118 MB)
    char* p = (char*)d_ws;
    auto carve = [&](size_t bytes) { char* r = p; p += (bytes + 255) & ~255UL; return r; };
    float* x      = (float*)carve(1048576L * 4);
    short* xh     = (short*)carve(1048576L * 2);
    short* xl     = (short*)carve(1048576L * 2);
    short* ench   = (short*)carve(1048576L * 2);
    short* encl   = (short*)carve(1048576L * 2);
    short* qh     = (short*)carve(2097152L * 2);   // head-major Q|K hi
    short* ql     = (short*)carve(2097152L * 2);   // head-major Q|K lo
    short* vth    = (short*)carve(1048576L * 2);   // transposed V hi
    short* vtl    = (short*)carve(1048576L * 2);
    short* oh     = (short*)carve(1048576L * 2);
    short* ol     = (short*)carve(1048576L * 2);
    short* t1h    = (short*)carve(4194304L * 2);   // FFN1 out hi
    short* t1l    = (short*)carve(4194304L * 2);
    float* part   = (float*)carve(6L * PSLAB * 4); // 6 K-split slabs
    short* WTLh   = (short*)carve(4194304L * 2);   // per-layer weights T hi
    short* WTLl   = (short*)carve(4194304L * 2);
    short* WTh    = (short*)carve(8192000L * 2);   // vocab chunk T hi
    short* WTl    = (short*)carve(8192000L * 2);

    const long PW = 262144L;    // 512*512
    const long HS = 1048576L;   // per attention operand slab

    embed_cvt_kernel<<<5120, 256, 0, stream>>>(tokens, emb, x, xh, xl,
                                               enc, ench, encl);

    for (int l = 0; l < NLAYER; ++l) {
        const float* bl = bqkvo + (long)l * 4096L;
        const float* bc = bl + 2048;
        const float* g  = lng + (long)l * 3 * 512;
        const float* bb = lnb + (long)l * 3 * 512;

        wtrans_layer_kernel<<<1024, 256, 0, stream>>>(Wqkvo, W1, W2, l, WTLh, WTLl);

        // ---- self-attention: QKV as z=6 fp32 partials + combine ----
        gemm_mfma_kernel<64,0,6><<<dim3(8, 32, 6), 256, 0, stream>>>(
            xh, xl, xh, xl, WTLh, WTLl, nullptr, part, nullptr, nullptr,
            256, 512, 512, 512, PW, 0, PSLAB, 256, /*aSwitchZ=*/6);
        qkv_combine_kernel<<<3072, 256, 0, stream>>>(
            part, bl, qh, ql, qh + HS, ql + HS, vth, vtl);
        attn_fused_kernel<true><<<dim3(32, 16), 128, 0, stream>>>(
            qh, ql, qh + HS, ql + HS, vth, vtl,
            selfA + (long)l * 16777216L, oh, ol);
        gemm_mfma_kernel<64,0,5><<<dim3(8, 32, 4), 256, 0, stream>>>(
            oh, ol, nullptr, nullptr, WTLh + 3*PW, WTLl + 3*PW, nullptr, part,
            nullptr, nullptr, 128, 512, 512, 512, 0, 0, PSLAB, 128, 0);
        add_ln_kernel<4><<<MROWS, 256, 0, stream>>>(
            x, part, PSLAB, bl + 3*512, g, bb, x, xh, xl);

        // ---- cross-attention: merged Qc+Kc+Vc as z=6 partials + combine ----
        gemm_mfma_kernel<64,0,6><<<dim3(8, 32, 6), 256, 0, stream>>>(
            xh, xl, ench, encl, WTLh + 4*PW, WTLl + 4*PW, nullptr, part,
            nullptr, nullptr, 256, 512, 512, 512, PW, 0, PSLAB, 256,
            /*aSwitchZ=*/2);
        qkv_combine_kernel<<<3072, 256, 0, stream>>>(
            part, bc, qh, ql, qh + HS, ql + HS, vth, vtl);
        attn_fused_kernel<false><<<dim3(32, 16), 128, 0, stream>>>(
            qh, ql, qh + HS, ql + HS, vth, vtl,
            crossA + (long)l * 16777216L, oh, ol);
        gemm_mfma_kernel<64,0,5><<<dim3(8, 32, 4), 256, 0, stream>>>(
            oh, ol, nullptr, nullptr, WTLh + 7*PW, WTLl + 7*PW, nullptr, part,
            nullptr, nullptr, 128, 512, 512, 512, 0, 0, PSLAB, 128, 0);
        add_ln_kernel<4><<<MROWS, 256, 0, stream>>>(
            x, part, PSLAB, bc + 3*512, g + 512, bb + 512, x, xh, xl);

        // ---- FFN ----
        gemm_mfma_kernel<64,1,2><<<dim3(32, 32, 1), 256, 0, stream>>>(
            xh, xl, nullptr, nullptr, WTLh + 2097152L, WTLl + 2097152L,
            b1 + (long)l * 2048, nullptr, t1h, t1l,
            512, 512, 512, 2048, 0, 0, 0, 0, 0);
        gemm_mfma_kernel<64,0,5><<<dim3(8, 32, 4), 256, 0, stream>>>(
            t1h, t1l, nullptr, nullptr, WTLh + 3145728L, WTLl + 3145728L,
            nullptr, part, nullptr, nullptr,
            512, 2048, 2048, 512, 0, 0, PSLAB, 512, 0);
        add_ln_kernel<4><<<MROWS, 256, 0, stream>>>(
            x, part, PSLAB, b2 + (long)l * 512, g + 1024, bb + 1024, x, xh, xl);
    }

    // ---- final vocab projection, two 16000-wide chunks ----
    for (int c = 0; c < 2; ++c) {
        wtrans_kernel<<<dim3(250, 8, 1), 256, 0, stream>>>(
            Wout + c * 16000, WTh, WTl, 512, VOCAB);
        gemm_mfma_kernel<128,0,0><<<dim3(125, 16, 1), 256, 0, stream>>>(
            xh, xl, nullptr, nullptr, WTh, WTl, bout + c * 16000,
            out + c * 16000, nullptr, nullptr,
            512, 512, 512, VOCAB, 0, 0, 0, 0, 0);
    }
}

// Round 11
// 1367.041 us; speedup vs baseline: 1.0595x; 1.0595x over previous
//
#include <hip/hip_runtime.h>
#include <hip/hip_bf16.h>

// ---------------------------------------------------------------------------
// Transformer decoder, fp32 I/O, split-bf16 MFMA everywhere.
// R11 = R8 + T3-minimum 2-phase (LDS double-buffer, 1 barrier/K-step) on all
// in-layer GEMMs; FFN1 at 64^2 grid 1024. Vocab unchanged (128^2, 1-buf).
// B=2, ST=SS=1024, D=512, H=8, DK=64, L=4, DFF=2048, V=32000.
// ---------------------------------------------------------------------------

#define D_MODEL 512
#define NHEAD   8
#define DKH     64
#define SEQ     1024
#define NLAYER  4
#define DFF_    2048
#define VOCAB   32000
#define BATCH   2
#define MROWS   (BATCH*SEQ)   // 2048
#define PSLAB   1048576L

typedef short bf16x8 __attribute__((ext_vector_type(8)));
typedef short short4v __attribute__((ext_vector_type(4)));
typedef float f32x4  __attribute__((ext_vector_type(4)));

static __device__ __forceinline__ short f2bf(float f) {
    __hip_bfloat16 h = __float2bfloat16(f);
    return *reinterpret_cast<short*>(&h);
}
static __device__ __forceinline__ float bf2f(short s) {
    __hip_bfloat16 h = *reinterpret_cast<__hip_bfloat16*>(&s);
    return __bfloat162float(h);
}
static __device__ __forceinline__ void gld16(const void* g, void* l) {
    __builtin_amdgcn_global_load_lds(
        (__attribute__((address_space(1))) void*)(void*)g,
        (__attribute__((address_space(3))) void*)l, 16, 0, 0);
}

// ---------------- embedding + positional encoding + hi/lo -------------------
__global__ __launch_bounds__(256) void embed_pe_kernel(
    const int* __restrict__ tokens, const float* __restrict__ emb,
    float* __restrict__ x, short* __restrict__ xh, short* __restrict__ xl)
{
    long idx = (long)blockIdx.x * 256 + threadIdx.x;   // over 1,048,576
    int  d   = (int)(idx & (D_MODEL - 1));
    long row = idx >> 9;
    int  s   = (int)(row & (SEQ - 1));
    int  tok = tokens[row];
    float twoi = (float)((d >> 1) << 1);
    float div  = expf(twoi * (-9.210340371976184f / 512.0f));
    float arg  = (float)s * div;
    float pe   = (d & 1) ? cosf(arg) : sinf(arg);
    float v = emb[(long)tok * D_MODEL + d] * 22.62741699796952f + pe; // sqrt(512)
    x[idx] = v;
    short h = f2bf(v);
    xh[idx] = h;
    xl[idx] = f2bf(v - bf2f(h));
}

// ---------------- fp32 -> bf16 hi/lo ----------------------------------------
__global__ __launch_bounds__(256) void cvt_kernel(
    const float* __restrict__ in, short* __restrict__ h, short* __restrict__ l)
{
    long e = ((long)blockIdx.x * 256 + threadIdx.x) * 4;
    float4 v = *(const float4*)&in[e];
    float f[4] = {v.x, v.y, v.z, v.w};
#pragma unroll
    for (int i = 0; i < 4; ++i) {
        short hh = f2bf(f[i]);
        h[e + i] = hh;
        l[e + i] = f2bf(f[i] - bf2f(hh));
    }
}

// ---------------- weight transpose-convert: W[K,N] -> WT[N,K] hi/lo ---------
__global__ __launch_bounds__(256) void wtrans_kernel(
    const float* __restrict__ W, short* __restrict__ Th, short* __restrict__ Tl,
    int K, int ldW)
{
    const int n0 = blockIdx.x * 64, k0 = blockIdx.y * 64;
    __shared__ float tile[64][65];
    const int t = threadIdx.x;
#pragma unroll
    for (int i = 0; i < 4; ++i) {
        int e = t + i * 256; int kk = e >> 4; int nn = (e & 15) * 4;
        float4 v = *(const float4*)&W[(long)(k0 + kk) * ldW + n0 + nn];
        tile[kk][nn] = v.x; tile[kk][nn + 1] = v.y;
        tile[kk][nn + 2] = v.z; tile[kk][nn + 3] = v.w;
    }
    __syncthreads();
    const int n = t >> 2, ks = (t & 3) * 16;
    short h8[16], l8[16];
#pragma unroll
    for (int j = 0; j < 16; ++j) {
        float f = tile[ks + j][n];
        short h = f2bf(f);
        h8[j] = h;
        l8[j] = f2bf(f - bf2f(h));
    }
    long base = (long)(n0 + n) * K + k0 + ks;
    *(bf16x8*)&Th[base]     = *(bf16x8*)&h8[0];
    *(bf16x8*)&Th[base + 8] = *(bf16x8*)&h8[8];
    *(bf16x8*)&Tl[base]     = *(bf16x8*)&l8[0];
    *(bf16x8*)&Tl[base + 8] = *(bf16x8*)&l8[8];
}

// ---------------- merged per-layer weight transpose (10 matrices) -----------
__global__ __launch_bounds__(256) void wtrans_layer_kernel(
    const float* __restrict__ Wqkvo, const float* __restrict__ W1,
    const float* __restrict__ W2, int l,
    short* __restrict__ Th, short* __restrict__ Tl)
{
    const int j = blockIdx.x;
    const float* W; int ldW, K; long dstOff; int n0, k0;
    if (j < 512) {
        int mat = j >> 6, tile_ = j & 63;
        W = Wqkvo + (long)l * 2097152L + (long)mat * 262144L;
        ldW = 512; K = 512; dstOff = (long)mat * 262144L;
        n0 = (tile_ & 7) * 64; k0 = (tile_ >> 3) * 64;
    } else if (j < 768) {
        int t2 = j - 512;
        W = W1 + (long)l * 1048576L; ldW = 2048; K = 512; dstOff = 2097152L;
        n0 = (t2 & 31) * 64; k0 = (t2 >> 5) * 64;
    } else {
        int t3 = j - 768;
        W = W2 + (long)l * 1048576L; ldW = 512; K = 2048; dstOff = 3145728L;
        n0 = (t3 & 7) * 64; k0 = (t3 >> 3) * 64;
    }
    __shared__ float tile[64][65];
    const int t = threadIdx.x;
#pragma unroll
    for (int i = 0; i < 4; ++i) {
        int e = t + i * 256; int kk = e >> 4; int nn = (e & 15) * 4;
        float4 v = *(const float4*)&W[(long)(k0 + kk) * ldW + n0 + nn];
        tile[kk][nn] = v.x; tile[kk][nn + 1] = v.y;
        tile[kk][nn + 2] = v.z; tile[kk][nn + 3] = v.w;
    }
    __syncthreads();
    const int n = t >> 2, ks = (t & 3) * 16;
    short h8[16], l8[16];
#pragma unroll
    for (int j2 = 0; j2 < 16; ++j2) {
        float f = tile[ks + j2][n];
        short h = f2bf(f);
        h8[j2] = h;
        l8[j2] = f2bf(f - bf2f(h));
    }
    long base = dstOff + (long)(n0 + n) * K + k0 + ks;
    *(bf16x8*)&Th[base]     = *(bf16x8*)&h8[0];
    *(bf16x8*)&Th[base + 8] = *(bf16x8*)&h8[8];
    *(bf16x8*)&Tl[base]     = *(bf16x8*)&l8[0];
    *(bf16x8*)&Tl[base + 8] = *(bf16x8*)&l8[8];
}

// ---------------- split-bf16 MFMA GEMM (rect tiles, optional 2-phase dbuf) --
// C[M,N] = act((Ah+Al)[M,Keff]@(Bh+Bl)^T + bias), K-window at z*kOff.
// MODE 0: fp32+bias. MODE 2: bf16 hi/lo+bias(+relu). MODE 3: head-major attn
// operand w/ dk swizzle (z==vtZ -> direct transposed V; z==scaledZ -> *0.125).
// MODE 5: fp32 partial, no bias.
// DBUF: double-buffered LDS, STAGE(k+1) issued before compute(k), one barrier
// per K-step (T3-minimum 2-phase).
template<int BM, int BN, int ACT, int MODE, bool DBUF>
__global__ __launch_bounds__(256) void gemm_mfma_kernel(
    const short* __restrict__ Ah, const short* __restrict__ Al,
    const short* __restrict__ Bh, const short* __restrict__ Bl,
    const float* __restrict__ bias, float* __restrict__ C,
    short* __restrict__ Ch, short* __restrict__ Cl,
    short* __restrict__ VTh, short* __restrict__ VTl,
    int Keff, int ldA, int ldB, int ldc,
    long zB, long zBias, long zC, int kOff, int scaledZ, int vtZ)
{
    constexpr int NB   = DBUF ? 2 : 1;
    constexpr int MT_M = BM / 32;
    constexpr int MT_N = BN / 32;
    const long z = blockIdx.z;
    Bh += z * zB; Bl += z * zB;
    if (MODE != 5) bias += z * zBias;

    const int n0 = blockIdx.x * BN, m0 = blockIdx.y * BM;
    const int t = threadIdx.x;
    const int w = t >> 6, lane = t & 63;
    const int wm = w >> 1, wn = w & 1;
    const int lr = lane & 15, ks = lane >> 4;

    __shared__ short sAh[NB][BM * 32], sAl[NB][BM * 32];
    __shared__ short sBh[NB][BN * 32], sBl[NB][BN * 32];

    f32x4 acc[MT_M][MT_N];
#pragma unroll
    for (int i = 0; i < MT_M; ++i)
#pragma unroll
        for (int j = 0; j < MT_N; ++j) acc[i][j] = (f32x4){0.f, 0.f, 0.f, 0.f};

    const long rowA = ((long)m0 * ldA + (long)z * kOff) * 2;   // bytes
    const long rowB = ((long)n0 * ldB + (long)z * kOff) * 2;

    auto STAGE = [&](int buf, int k0) {
#pragma unroll
        for (int i = 0; i < BM / 64; ++i) {
            const int  L = i * 4096 + t * 16;
            const int  r = L >> 6, s = L & 63;
            const long gb = ((long)r * ldA + k0) * 2 + s;
            gld16((const char*)Ah + rowA + gb, (char*)&sAh[buf][0] + L);
            gld16((const char*)Al + rowA + gb, (char*)&sAl[buf][0] + L);
        }
#pragma unroll
        for (int i = 0; i < BN / 64; ++i) {
            const int  L = i * 4096 + t * 16;
            const int  r = L >> 6, s = L & 63;
            const long gb = ((long)r * ldB + k0) * 2 + s;
            gld16((const char*)Bh + rowB + gb, (char*)&sBh[buf][0] + L);
            gld16((const char*)Bl + rowB + gb, (char*)&sBl[buf][0] + L);
        }
    };
    auto COMPUTE = [&](int buf) {
        bf16x8 ah[MT_M], al[MT_M], bh[MT_N], bl[MT_N];
#pragma unroll
        for (int mt = 0; mt < MT_M; ++mt) {
            int row = wm * (BM / 2) + mt * 16 + lr;
            ah[mt] = *(const bf16x8*)&sAh[buf][row * 32 + ks * 8];
            al[mt] = *(const bf16x8*)&sAl[buf][row * 32 + ks * 8];
        }
#pragma unroll
        for (int nt = 0; nt < MT_N; ++nt) {
            int col = wn * (BN / 2) + nt * 16 + lr;
            bh[nt] = *(const bf16x8*)&sBh[buf][col * 32 + ks * 8];
            bl[nt] = *(const bf16x8*)&sBl[buf][col * 32 + ks * 8];
        }
#pragma unroll
        for (int mt = 0; mt < MT_M; ++mt)
#pragma unroll
            for (int nt = 0; nt < MT_N; ++nt) {
                acc[mt][nt] = __builtin_amdgcn_mfma_f32_16x16x32_bf16(
                    ah[mt], bh[nt], acc[mt][nt], 0, 0, 0);
                acc[mt][nt] = __builtin_amdgcn_mfma_f32_16x16x32_bf16(
                    ah[mt], bl[nt], acc[mt][nt], 0, 0, 0);
                acc[mt][nt] = __builtin_amdgcn_mfma_f32_16x16x32_bf16(
                    al[mt], bh[nt], acc[mt][nt], 0, 0, 0);
            }
    };

    if (DBUF) {
        STAGE(0, 0);
        __syncthreads();
        int cur = 0;
        for (int k0 = 0; k0 < Keff; k0 += 32) {
            if (k0 + 32 < Keff) STAGE(cur ^ 1, k0 + 32);   // prefetch next tile
            COMPUTE(cur);
            __syncthreads();                               // one barrier/K-step
            cur ^= 1;
        }
    } else {
        for (int k0 = 0; k0 < Keff; k0 += 32) {
            STAGE(0, k0);
            __syncthreads();
            COMPUTE(0);
            __syncthreads();
        }
    }

    const int rq = lane >> 4, cq = lane & 15;
#pragma unroll
    for (int mt = 0; mt < MT_M; ++mt)
#pragma unroll
        for (int nt = 0; nt < MT_N; ++nt) {
            int gr0 = m0 + wm * (BM / 2) + mt * 16 + rq * 4;
            int gc  = n0 + wn * (BN / 2) + nt * 16 + cq;
            float vv[4];
            float bv = (MODE == 5) ? 0.f : bias[gc];
#pragma unroll
            for (int i = 0; i < 4; ++i) {
                float v = acc[mt][nt][i] + bv;
                if (ACT == 1) v = fmaxf(v, 0.f);
                vv[i] = v;
            }
            if (MODE == 0 || MODE == 5) {
#pragma unroll
                for (int i = 0; i < 4; ++i)
                    C[(long)(gr0 + i) * ldc + gc + z * zC] = vv[i];
            } else if (MODE == 2) {
#pragma unroll
                for (int i = 0; i < 4; ++i) {
                    long off = (long)(gr0 + i) * ldc + gc;
                    short h = f2bf(vv[i]);
                    Ch[off] = h;
                    Cl[off] = f2bf(vv[i] - bf2f(h));
                }
            } else {               // MODE 3
                if ((int)z == vtZ) {
                    int b = gr0 >> 10, s0 = gr0 & (SEQ - 1);
                    int hh2 = gc >> 6, dk = gc & 63;
                    int swz = (((dk >> 1) & 3) << 3) | (((dk >> 3) & 1) << 5);
                    long base = (((long)(b * NHEAD + hh2)) * 64 + dk) * 1024
                              + (long)(((s0 & ~7) ^ swz) | (s0 & 7));
                    short4v hv, lv;
#pragma unroll
                    for (int i = 0; i < 4; ++i) {
                        short h = f2bf(vv[i]);
                        hv[i] = h;
                        lv[i] = f2bf(vv[i] - bf2f(h));
                    }
                    *(short4v*)&VTh[base] = hv;
                    *(short4v*)&VTl[base] = lv;
                } else {
                    float sc = ((int)z == scaledZ) ? 0.125f : 1.f;
#pragma unroll
                    for (int i = 0; i < 4; ++i) {
                        float v2 = vv[i] * sc;
                        int gr = gr0 + i;
                        int b = gr >> 10, s = gr & (SEQ - 1);
                        int hh2 = gc >> 6, dk = gc & 63;
                        int dks = dk ^ (((s >> 1) & 7) << 3);
                        long oidx = z * zC +
                            (((long)(b * NHEAD + hh2)) * SEQ + s) * 64 + dks;
                        short h = f2bf(v2);
                        Ch[oidx] = h;
                        Cl[oidx] = f2bf(v2 - bf2f(h));
                    }
                }
            }
        }
}

// ---------------- Qc combine: part0+part1+bias -> *0.125 -> MODE3 layout ----
__global__ __launch_bounds__(256) void qc_combine_kernel(
    const float* __restrict__ p0, const float* __restrict__ p1,
    const float* __restrict__ bias, short* __restrict__ Qh, short* __restrict__ Ql)
{
    long idx = (long)blockIdx.x * 256 + threadIdx.x;   // 262144 total
    int gr = (int)(idx >> 7);
    int gc4 = (int)(idx & 127) * 4;
    float4 a = *(const float4*)&p0[(long)gr * 512 + gc4];
    float4 b2 = *(const float4*)&p1[(long)gr * 512 + gc4];
    float4 bv = *(const float4*)&bias[gc4];
    float v[4] = {(a.x + b2.x + bv.x) * 0.125f, (a.y + b2.y + bv.y) * 0.125f,
                  (a.z + b2.z + bv.z) * 0.125f, (a.w + b2.w + bv.w) * 0.125f};
    int b = gr >> 10, s = gr & (SEQ - 1);
    int hh = gc4 >> 6, dk4 = gc4 & 63;
    int dks = dk4 ^ (((s >> 1) & 7) << 3);
    long o = (((long)(b * NHEAD + hh)) * SEQ + s) * 64 + dks;
    short4v hv, lv;
#pragma unroll
    for (int i = 0; i < 4; ++i) {
        short h = f2bf(v[i]);
        hv[i] = h;
        lv[i] = f2bf(v[i] - bf2f(h));
    }
    *(short4v*)&Qh[o] = hv;
    *(short4v*)&Ql[o] = lv;
}

// ---------------- fused attention: 32 q-rows, 2 waves, 2 blocks/CU ----------
template<bool CAUSAL>
__global__ __launch_bounds__(128) void attn_fused_kernel(
    const short* __restrict__ Qh, const short* __restrict__ Ql,
    const short* __restrict__ Kh, const short* __restrict__ Kl,
    const short* __restrict__ VTh, const short* __restrict__ VTl,
    float* __restrict__ attn, short* __restrict__ Oh, short* __restrict__ Ol)
{
    const int strip = blockIdx.x, bh = blockIdx.y;
    const int q0 = strip * 32;
    const int t = threadIdx.x, w = t >> 6, lane = t & 63;
    const int lr = lane & 15, ks = lane >> 4;
    const int rq = lane >> 4, cq = lane & 15;
    const int sxq = (lr >> 1) & 7;

    __shared__ short sKh[2][64*64], sKl[2][64*64];   // 32 KB
    __shared__ short sVh[2][64*64], sVl[2][64*64];   // 32 KB
    __shared__ short sPh[2][16*80], sPl[2][16*80];   // 10 KB

    const int diag  = strip >> 1;
    const int ktmax = CAUSAL ? diag + 1 : 16;

    {
        const long qb = ((long)bh * SEQ + q0) * 128;
#pragma unroll
        for (int i2 = 0; i2 < 2; ++i2) {
            int L = i2 * 2048 + t * 16; int r = L >> 7, off = L & 127;
            gld16((const char*)Qh + qb + (long)r*128 + off, (char*)&sVh[0][0] + L);
            gld16((const char*)Ql + qb + (long)r*128 + off, (char*)&sVl[0][0] + L);
        }
    }
    __syncthreads();
    bf16x8 qa[2][2];
#pragma unroll
    for (int k0 = 0; k0 < 2; ++k0) {
        int o = (w*16 + lr) * 64 + ((k0*32 + ks*8) ^ (sxq << 3));
        qa[k0][0] = *(const bf16x8*)&sVh[0][o];
        qa[k0][1] = *(const bf16x8*)&sVl[0][o];
    }
    __syncthreads();

    auto stageK = [&](int buf, int kt) {
        const long kb = ((long)bh * SEQ + kt*64) * 128;
#pragma unroll
        for (int i2 = 0; i2 < 4; ++i2) {
            int L = i2*2048 + t*16; int r = L >> 7, off = L & 127;
            gld16((const char*)Kh + kb + (long)r*128 + off, (char*)&sKh[buf][0] + L);
            gld16((const char*)Kl + kb + (long)r*128 + off, (char*)&sKl[buf][0] + L);
        }
    };
    auto stageV = [&](int buf, int kt) {
        const long vb = ((long)bh * 64) * 2048 + (long)kt * 128;
#pragma unroll
        for (int i2 = 0; i2 < 4; ++i2) {
            int L = i2*2048 + t*16; int r = L >> 7, off = L & 127;
            gld16((const char*)VTh + vb + (long)r*2048 + off, (char*)&sVh[buf][0] + L);
            gld16((const char*)VTl + vb + (long)r*2048 + off, (char*)&sVl[buf][0] + L);
        }
    };
    auto scoresOf = [&](int buf, int kt, f32x4* sc) {
#pragma unroll
        for (int nt = 0; nt < 4; ++nt) sc[nt] = (f32x4){0.f, 0.f, 0.f, 0.f};
#pragma unroll
        for (int k0 = 0; k0 < 2; ++k0) {
            bf16x8 kh[4], kl[4];
#pragma unroll
            for (int nt = 0; nt < 4; ++nt) {
                int o = (nt*16 + lr) * 64 + ((k0*32 + ks*8) ^ (sxq << 3));
                kh[nt] = *(const bf16x8*)&sKh[buf][o];
                kl[nt] = *(const bf16x8*)&sKl[buf][o];
            }
#pragma unroll
            for (int nt = 0; nt < 4; ++nt) {
                sc[nt] = __builtin_amdgcn_mfma_f32_16x16x32_bf16(
                    qa[k0][0], kh[nt], sc[nt], 0, 0, 0);
                sc[nt] = __builtin_amdgcn_mfma_f32_16x16x32_bf16(
                    qa[k0][0], kl[nt], sc[nt], 0, 0, 0);
                sc[nt] = __builtin_amdgcn_mfma_f32_16x16x32_bf16(
                    qa[k0][1], kh[nt], sc[nt], 0, 0, 0);
            }
        }
        if (CAUSAL && kt == diag) {
            int row = q0 + w*16 + rq*4;
#pragma unroll
            for (int nt = 0; nt < 4; ++nt) {
                int col = kt*64 + nt*16 + cq;
#pragma unroll
                for (int i = 0; i < 4; ++i)
                    if (col > row + i) sc[nt][i] = -1e9f;
            }
        }
    };

    // ---- pass 1: online max + sum ----
    float m[4]   = {-3e38f, -3e38f, -3e38f, -3e38f};
    float sum[4] = {0.f, 0.f, 0.f, 0.f};
    int cur = 0;
    stageK(0, 0);
    __syncthreads();
    for (int kt = 0; kt < ktmax; ++kt) {
        if (kt + 1 < ktmax) stageK(cur ^ 1, kt + 1);
        f32x4 sc[4];
        scoresOf(cur, kt, sc);
#pragma unroll
        for (int i = 0; i < 4; ++i) {
            float tm = fmaxf(fmaxf(sc[0][i], sc[1][i]), fmaxf(sc[2][i], sc[3][i]));
#pragma unroll
            for (int d2 = 1; d2 <= 8; d2 <<= 1) tm = fmaxf(tm, __shfl_xor(tm, d2, 64));
            float mn = fmaxf(m[i], tm);
            float ps = __expf(sc[0][i] - mn) + __expf(sc[1][i] - mn)
                     + __expf(sc[2][i] - mn) + __expf(sc[3][i] - mn);
#pragma unroll
            for (int d2 = 1; d2 <= 8; d2 <<= 1) ps += __shfl_xor(ps, d2, 64);
            sum[i] = sum[i] * __expf(m[i] - mn) + ps;
            m[i] = mn;
        }
        __syncthreads();
        cur ^= 1;
    }
    float inv[4];
#pragma unroll
    for (int i = 0; i < 4; ++i) inv[i] = 1.f / sum[i];

    // ---- pass 2: recompute, probs out, PV ----
    f32x4 acco[4];
#pragma unroll
    for (int nt = 0; nt < 4; ++nt) acco[nt] = (f32x4){0.f, 0.f, 0.f, 0.f};

    cur = 0;
    stageK(0, 0); stageV(0, 0);
    __syncthreads();
    for (int kt = 0; kt < 16; ++kt) {
        if (kt >= ktmax) {
#pragma unroll
            for (int nt = 0; nt < 4; ++nt)
#pragma unroll
                for (int i = 0; i < 4; ++i)
                    attn[((long)bh << 20) + ((long)(q0 + w*16 + rq*4 + i) << 10)
                         + kt*64 + nt*16 + cq] = 0.f;
            continue;
        }
        if (kt + 1 < ktmax) { stageK(cur ^ 1, kt + 1); stageV(cur ^ 1, kt + 1); }
        f32x4 sc[4];
        scoresOf(cur, kt, sc);
#pragma unroll
        for (int nt = 0; nt < 4; ++nt)
#pragma unroll
            for (int i = 0; i < 4; ++i) {
                float p = __expf(sc[nt][i] - m[i]) * inv[i];
                attn[((long)bh << 20) + ((long)(q0 + w*16 + rq*4 + i) << 10)
                     + kt*64 + nt*16 + cq] = p;
                short ph = f2bf(p);
                sPh[w][(rq*4 + i)*80 + nt*16 + cq] = ph;
                sPl[w][(rq*4 + i)*80 + nt*16 + cq] = f2bf(p - bf2f(ph));
            }
#pragma unroll
        for (int k0 = 0; k0 < 2; ++k0) {
            bf16x8 pah = *(const bf16x8*)&sPh[w][lr*80 + k0*32 + ks*8];
            bf16x8 pal = *(const bf16x8*)&sPl[w][lr*80 + k0*32 + ks*8];
#pragma unroll
            for (int nt = 0; nt < 4; ++nt) {
                int dk = nt*16 + lr;
                int swz = (((dk >> 1) & 3) << 3) | (((dk >> 3) & 1) << 5);
                int koff = (k0*32 + ks*8) ^ swz;
                bf16x8 vh8 = *(const bf16x8*)&sVh[cur][dk*64 + koff];
                bf16x8 vl8 = *(const bf16x8*)&sVl[cur][dk*64 + koff];
                acco[nt] = __builtin_amdgcn_mfma_f32_16x16x32_bf16(
                    pah, vh8, acco[nt], 0, 0, 0);
                acco[nt] = __builtin_amdgcn_mfma_f32_16x16x32_bf16(
                    pah, vl8, acco[nt], 0, 0, 0);
                acco[nt] = __builtin_amdgcn_mfma_f32_16x16x32_bf16(
                    pal, vh8, acco[nt], 0, 0, 0);
            }
        }
        __syncthreads();
        cur ^= 1;
    }

    const int b = bh >> 3, hh_ = bh & 7;
#pragma unroll
    for (int nt = 0; nt < 4; ++nt)
#pragma unroll
        for (int i = 0; i < 4; ++i) {
            float v = acco[nt][i];
            long oidx = ((long)(b * SEQ + q0 + w*16 + rq*4 + i)) * D_MODEL
                      + hh_*64 + nt*16 + cq;
            short h2 = f2bf(v);
            Oh[oidx] = h2;
            Ol[oidx] = f2bf(v - bf2f(h2));
        }
}

// ---------------- residual + NS partial slabs + bias + LayerNorm + hi/lo ----
template<int NS>
__global__ __launch_bounds__(256) void add_ln_kernel(
    const float* __restrict__ xin, const float* __restrict__ part, long PS,
    const float* __restrict__ bias,
    const float* __restrict__ g, const float* __restrict__ bb,
    float* __restrict__ xout, short* __restrict__ xh, short* __restrict__ xl)
{
    long row = blockIdx.x;
    const float* xr = xin + row * D_MODEL;
    float*       xo = xout+ row * D_MODEL;
    short*       hh = xh  + row * D_MODEL;
    short*       ll = xl  + row * D_MODEL;
    int t = threadIdx.x;

    float a0 = xr[t]       + bias[t];
    float a1 = xr[t + 256] + bias[t + 256];
#pragma unroll
    for (int s2 = 0; s2 < NS; ++s2) {
        a0 += part[s2 * PS + row * D_MODEL + t];
        a1 += part[s2 * PS + row * D_MODEL + t + 256];
    }

    float s = a0 + a1;
#pragma unroll
    for (int m = 32; m; m >>= 1) s += __shfl_xor(s, m, 64);
    __shared__ float red1[4];
    __shared__ float red2[4];
    int w = t >> 6, lane = t & 63;
    if (lane == 0) red1[w] = s;
    __syncthreads();
    float mean = (red1[0] + red1[1] + red1[2] + red1[3]) * (1.f / 512.f);

    float d0 = a0 - mean, d1 = a1 - mean;
    float q = d0 * d0 + d1 * d1;
#pragma unroll
    for (int m = 32; m; m >>= 1) q += __shfl_xor(q, m, 64);
    if (lane == 0) red2[w] = q;
    __syncthreads();
    float var  = (red2[0] + red2[1] + red2[2] + red2[3]) * (1.f / 512.f);
    float rstd = rsqrtf(var + 1e-5f);

    float r0 = d0 * rstd * g[t]       + bb[t];
    float r1 = d1 * rstd * g[t + 256] + bb[t + 256];
    xo[t] = r0; xo[t + 256] = r1;
    short h0 = f2bf(r0); hh[t] = h0;       ll[t] = f2bf(r0 - bf2f(h0));
    short h1 = f2bf(r1); hh[t + 256] = h1; ll[t + 256] = f2bf(r1 - bf2f(h1));
}

// ---------------------------------------------------------------------------
extern "C" void kernel_launch(void* const* d_in, const int* in_sizes, int n_in,
                              void* d_out, int out_size, void* d_ws, size_t ws_size,
                              hipStream_t stream)
{
    const int*   tokens = (const int*)  d_in[0];
    const float* enc    = (const float*)d_in[1];
    const float* emb    = (const float*)d_in[3];
    const float* Wqkvo  = (const float*)d_in[4];   // [L,2,4,D,D]
    const float* bqkvo  = (const float*)d_in[5];   // [L,2,4,D]
    const float* W1     = (const float*)d_in[6];   // [L,D,DFF]
    const float* b1     = (const float*)d_in[7];
    const float* W2     = (const float*)d_in[8];   // [L,DFF,D]
    const float* b2     = (const float*)d_in[9];
    const float* lng    = (const float*)d_in[10];  // [L,3,D]
    const float* lnb    = (const float*)d_in[11];
    const float* Wout   = (const float*)d_in[12];  // [D,V]
    const float* bout   = (const float*)d_in[13];

    float* out    = (float*)d_out;
    float* selfA  = out + 65536000L;
    float* crossA = selfA + 67108864L;

    // workspace carve (~112 MB)
    char* p = (char*)d_ws;
    auto carve = [&](size_t bytes) { char* r = p; p += (bytes + 255) & ~255UL; return r; };
    float* x      = (float*)carve(1048576L * 4);
    short* xh     = (short*)carve(1048576L * 2);
    short* xl     = (short*)carve(1048576L * 2);
    short* ench   = (short*)carve(1048576L * 2);
    short* encl   = (short*)carve(1048576L * 2);
    short* qh     = (short*)carve(2097152L * 2);   // head-major Q|K hi
    short* ql     = (short*)carve(2097152L * 2);   // head-major Q|K lo
    short* vth    = (short*)carve(1048576L * 2);   // transposed V hi
    short* vtl    = (short*)carve(1048576L * 2);
    short* oh     = (short*)carve(1048576L * 2);
    short* ol     = (short*)carve(1048576L * 2);
    short* t1h    = (short*)carve(4194304L * 2);   // FFN1 out hi
    short* t1l    = (short*)carve(4194304L * 2);
    float* part   = (float*)carve(4L * PSLAB * 4); // 4 K-split slabs
    short* WTLh   = (short*)carve(4194304L * 2);   // per-layer weights T hi
    short* WTLl   = (short*)carve(4194304L * 2);
    short* WTh    = (short*)carve(8192000L * 2);   // vocab chunk T hi
    short* WTl    = (short*)carve(8192000L * 2);

    const long PW = 262144L;    // 512*512
    const long HS = 1048576L;   // per attention operand slab

    embed_pe_kernel<<<4096, 256, 0, stream>>>(tokens, emb, x, xh, xl);
    cvt_kernel<<<1024, 256, 0, stream>>>(enc, ench, encl);

    for (int l = 0; l < NLAYER; ++l) {
        const float* bl = bqkvo + (long)l * 4096L;
        const float* bc = bl + 2048;
        const float* g  = lng + (long)l * 3 * 512;
        const float* bb = lnb + (long)l * 3 * 512;

        wtrans_layer_kernel<<<1024, 256, 0, stream>>>(Wqkvo, W1, W2, l, WTLh, WTLl);

        // ---- self-attention ----
        gemm_mfma_kernel<64,64,0,3,true><<<dim3(8, 32, 3), 256, 0, stream>>>(
            xh, xl, WTLh, WTLl, bl, nullptr, qh, ql, vth, vtl,
            512, 512, 512, 0, PW, 512, HS, 0, /*scaledZ=*/0, /*vtZ=*/2);
        attn_fused_kernel<true><<<dim3(32, 16), 128, 0, stream>>>(
            qh, ql, qh + HS, ql + HS, vth, vtl,
            selfA + (long)l * 16777216L, oh, ol);
        gemm_mfma_kernel<64,64,0,5,true><<<dim3(8, 32, 2), 256, 0, stream>>>(
            oh, ol, WTLh + 3*PW, WTLl + 3*PW, nullptr, part, nullptr, nullptr,
            nullptr, nullptr, 256, 512, 512, 512, 0, 0, PSLAB, 256, -1, -1);
        add_ln_kernel<2><<<MROWS, 256, 0, stream>>>(
            x, part, PSLAB, bl + 3*512, g, bb, x, xh, xl);

        // ---- cross-attention ----
        gemm_mfma_kernel<64,64,0,5,true><<<dim3(8, 32, 2), 256, 0, stream>>>(
            xh, xl, WTLh + 4*PW, WTLl + 4*PW, nullptr, part, nullptr, nullptr,
            nullptr, nullptr, 256, 512, 512, 512, 0, 0, PSLAB, 256, -1, -1);
        qc_combine_kernel<<<1024, 256, 0, stream>>>(part, part + PSLAB, bc, qh, ql);
        gemm_mfma_kernel<64,64,0,3,true><<<dim3(8, 32, 2), 256, 0, stream>>>(
            ench, encl, WTLh + 5*PW, WTLl + 5*PW, bc + 512, nullptr,
            qh + HS, ql + HS, vth, vtl,
            512, 512, 512, 0, PW, 512, HS, 0, /*scaledZ=*/-1, /*vtZ=*/1);
        attn_fused_kernel<false><<<dim3(32, 16), 128, 0, stream>>>(
            qh, ql, qh + HS, ql + HS, vth, vtl,
            crossA + (long)l * 16777216L, oh, ol);
        gemm_mfma_kernel<64,64,0,5,true><<<dim3(8, 32, 2), 256, 0, stream>>>(
            oh, ol, WTLh + 7*PW, WTLl + 7*PW, nullptr, part, nullptr, nullptr,
            nullptr, nullptr, 256, 512, 512, 512, 0, 0, PSLAB, 256, -1, -1);
        add_ln_kernel<2><<<MROWS, 256, 0, stream>>>(
            x, part, PSLAB, bc + 3*512, g + 512, bb + 512, x, xh, xl);

        // ---- FFN ----
        gemm_mfma_kernel<64,64,1,2,true><<<dim3(32, 32, 1), 256, 0, stream>>>(
            xh, xl, WTLh + 2097152L, WTLl + 2097152L, b1 + (long)l * 2048,
            nullptr, t1h, t1l, nullptr, nullptr,
            512, 512, 512, 2048, 0, 0, 0, 0, -1, -1);
        gemm_mfma_kernel<64,64,0,5,true><<<dim3(8, 32, 4), 256, 0, stream>>>(
            t1h, t1l, WTLh + 3145728L, WTLl + 3145728L, nullptr, part,
            nullptr, nullptr, nullptr, nullptr,
            512, 2048, 2048, 512, 0, 0, PSLAB, 512, -1, -1);
        add_ln_kernel<4><<<MROWS, 256, 0, stream>>>(
            x, part, PSLAB, b2 + (long)l * 512, g + 1024, bb + 1024, x, xh, xl);
    }

    // ---- final vocab projection, two 16000-wide chunks (as R8) ----
    for (int c = 0; c < 2; ++c) {
        wtrans_kernel<<<dim3(250, 8, 1), 256, 0, stream>>>(
            Wout + c * 16000, WTh, WTl, 512, VOCAB);
        gemm_mfma_kernel<128,128,0,0,false><<<dim3(125, 16, 1), 256, 0, stream>>>(
            xh, xl, WTh, WTl, bout + c * 16000, out + c * 16000,
            nullptr, nullptr, nullptr, nullptr,
            512, 512, 512, VOCAB, 0, 0, 0, 0, -1, -1);
    }
}

// Round 12
// 1260.861 us; speedup vs baseline: 1.1487x; 1.0842x over previous
//
#include <hip/hip_runtime.h>
#include <hip/hip_bf16.h>

// ---------------------------------------------------------------------------
// Transformer decoder, fp32 I/O. GEMMs: A=bf16(hi), B=split-bf16 (2-product
// Ah*Bh + Ah*Bl). Attention internals keep full 3-product hi/lo. R11 schedule.
// B=2, ST=SS=1024, D=512, H=8, DK=64, L=4, DFF=2048, V=32000.
// ---------------------------------------------------------------------------

#define D_MODEL 512
#define NHEAD   8
#define DKH     64
#define SEQ     1024
#define NLAYER  4
#define DFF_    2048
#define VOCAB   32000
#define BATCH   2
#define MROWS   (BATCH*SEQ)   // 2048
#define PSLAB   1048576L

typedef short bf16x8 __attribute__((ext_vector_type(8)));
typedef short short4v __attribute__((ext_vector_type(4)));
typedef float f32x4  __attribute__((ext_vector_type(4)));

static __device__ __forceinline__ short f2bf(float f) {
    __hip_bfloat16 h = __float2bfloat16(f);
    return *reinterpret_cast<short*>(&h);
}
static __device__ __forceinline__ float bf2f(short s) {
    __hip_bfloat16 h = *reinterpret_cast<__hip_bfloat16*>(&s);
    return __bfloat162float(h);
}
static __device__ __forceinline__ void gld16(const void* g, void* l) {
    __builtin_amdgcn_global_load_lds(
        (__attribute__((address_space(1))) void*)(void*)g,
        (__attribute__((address_space(3))) void*)l, 16, 0, 0);
}

// ---------------- embedding + positional encoding + hi/lo -------------------
__global__ __launch_bounds__(256) void embed_pe_kernel(
    const int* __restrict__ tokens, const float* __restrict__ emb,
    float* __restrict__ x, short* __restrict__ xh, short* __restrict__ xl)
{
    long idx = (long)blockIdx.x * 256 + threadIdx.x;   // over 1,048,576
    int  d   = (int)(idx & (D_MODEL - 1));
    long row = idx >> 9;
    int  s   = (int)(row & (SEQ - 1));
    int  tok = tokens[row];
    float twoi = (float)((d >> 1) << 1);
    float div  = expf(twoi * (-9.210340371976184f / 512.0f));
    float arg  = (float)s * div;
    float pe   = (d & 1) ? cosf(arg) : sinf(arg);
    float v = emb[(long)tok * D_MODEL + d] * 22.62741699796952f + pe; // sqrt(512)
    x[idx] = v;
    short h = f2bf(v);
    xh[idx] = h;
    xl[idx] = f2bf(v - bf2f(h));
}

// ---------------- fp32 -> bf16 hi/lo ----------------------------------------
__global__ __launch_bounds__(256) void cvt_kernel(
    const float* __restrict__ in, short* __restrict__ h, short* __restrict__ l)
{
    long e = ((long)blockIdx.x * 256 + threadIdx.x) * 4;
    float4 v = *(const float4*)&in[e];
    float f[4] = {v.x, v.y, v.z, v.w};
#pragma unroll
    for (int i = 0; i < 4; ++i) {
        short hh = f2bf(f[i]);
        h[e + i] = hh;
        l[e + i] = f2bf(f[i] - bf2f(hh));
    }
}

// ---------------- weight transpose-convert: W[K,N] -> WT[N,K] hi/lo ---------
__global__ __launch_bounds__(256) void wtrans_kernel(
    const float* __restrict__ W, short* __restrict__ Th, short* __restrict__ Tl,
    int K, int ldW)
{
    const int n0 = blockIdx.x * 64, k0 = blockIdx.y * 64;
    __shared__ float tile[64][65];
    const int t = threadIdx.x;
#pragma unroll
    for (int i = 0; i < 4; ++i) {
        int e = t + i * 256; int kk = e >> 4; int nn = (e & 15) * 4;
        float4 v = *(const float4*)&W[(long)(k0 + kk) * ldW + n0 + nn];
        tile[kk][nn] = v.x; tile[kk][nn + 1] = v.y;
        tile[kk][nn + 2] = v.z; tile[kk][nn + 3] = v.w;
    }
    __syncthreads();
    const int n = t >> 2, ks = (t & 3) * 16;
    short h8[16], l8[16];
#pragma unroll
    for (int j = 0; j < 16; ++j) {
        float f = tile[ks + j][n];
        short h = f2bf(f);
        h8[j] = h;
        l8[j] = f2bf(f - bf2f(h));
    }
    long base = (long)(n0 + n) * K + k0 + ks;
    *(bf16x8*)&Th[base]     = *(bf16x8*)&h8[0];
    *(bf16x8*)&Th[base + 8] = *(bf16x8*)&h8[8];
    *(bf16x8*)&Tl[base]     = *(bf16x8*)&l8[0];
    *(bf16x8*)&Tl[base + 8] = *(bf16x8*)&l8[8];
}

// ---------------- merged per-layer weight transpose (10 matrices) -----------
__global__ __launch_bounds__(256) void wtrans_layer_kernel(
    const float* __restrict__ Wqkvo, const float* __restrict__ W1,
    const float* __restrict__ W2, int l,
    short* __restrict__ Th, short* __restrict__ Tl)
{
    const int j = blockIdx.x;
    const float* W; int ldW, K; long dstOff; int n0, k0;
    if (j < 512) {
        int mat = j >> 6, tile_ = j & 63;
        W = Wqkvo + (long)l * 2097152L + (long)mat * 262144L;
        ldW = 512; K = 512; dstOff = (long)mat * 262144L;
        n0 = (tile_ & 7) * 64; k0 = (tile_ >> 3) * 64;
    } else if (j < 768) {
        int t2 = j - 512;
        W = W1 + (long)l * 1048576L; ldW = 2048; K = 512; dstOff = 2097152L;
        n0 = (t2 & 31) * 64; k0 = (t2 >> 5) * 64;
    } else {
        int t3 = j - 768;
        W = W2 + (long)l * 1048576L; ldW = 512; K = 2048; dstOff = 3145728L;
        n0 = (t3 & 7) * 64; k0 = (t3 >> 3) * 64;
    }
    __shared__ float tile[64][65];
    const int t = threadIdx.x;
#pragma unroll
    for (int i = 0; i < 4; ++i) {
        int e = t + i * 256; int kk = e >> 4; int nn = (e & 15) * 4;
        float4 v = *(const float4*)&W[(long)(k0 + kk) * ldW + n0 + nn];
        tile[kk][nn] = v.x; tile[kk][nn + 1] = v.y;
        tile[kk][nn + 2] = v.z; tile[kk][nn + 3] = v.w;
    }
    __syncthreads();
    const int n = t >> 2, ks = (t & 3) * 16;
    short h8[16], l8[16];
#pragma unroll
    for (int j2 = 0; j2 < 16; ++j2) {
        float f = tile[ks + j2][n];
        short h = f2bf(f);
        h8[j2] = h;
        l8[j2] = f2bf(f - bf2f(h));
    }
    long base = dstOff + (long)(n0 + n) * K + k0 + ks;
    *(bf16x8*)&Th[base]     = *(bf16x8*)&h8[0];
    *(bf16x8*)&Th[base + 8] = *(bf16x8*)&h8[8];
    *(bf16x8*)&Tl[base]     = *(bf16x8*)&l8[0];
    *(bf16x8*)&Tl[base + 8] = *(bf16x8*)&l8[8];
}

// ---------------- 2-product MFMA GEMM: C = act(Ah@(Bh+Bl)^T + bias) ---------
// K-window at z*kOff. MODE 0: fp32+bias. MODE 2: bf16 hi/lo+bias(+relu).
// MODE 3: head-major attn operand w/ dk swizzle (z==vtZ -> transposed V;
// z==scaledZ -> *0.125). MODE 5: fp32 partial, no bias.
// DBUF: double-buffered LDS, STAGE(k+1) before compute(k), 1 barrier/K-step.
template<int BM, int BN, int ACT, int MODE, bool DBUF>
__global__ __launch_bounds__(256) void gemm_mfma_kernel(
    const short* __restrict__ Ah,
    const short* __restrict__ Bh, const short* __restrict__ Bl,
    const float* __restrict__ bias, float* __restrict__ C,
    short* __restrict__ Ch, short* __restrict__ Cl,
    short* __restrict__ VTh, short* __restrict__ VTl,
    int Keff, int ldA, int ldB, int ldc,
    long zB, long zBias, long zC, int kOff, int scaledZ, int vtZ)
{
    constexpr int NB   = DBUF ? 2 : 1;
    constexpr int MT_M = BM / 32;
    constexpr int MT_N = BN / 32;
    const long z = blockIdx.z;
    Bh += z * zB; Bl += z * zB;
    if (MODE != 5) bias += z * zBias;

    const int n0 = blockIdx.x * BN, m0 = blockIdx.y * BM;
    const int t = threadIdx.x;
    const int w = t >> 6, lane = t & 63;
    const int wm = w >> 1, wn = w & 1;
    const int lr = lane & 15, ks = lane >> 4;

    __shared__ short sAh[NB][BM * 32];
    __shared__ short sBh[NB][BN * 32], sBl[NB][BN * 32];

    f32x4 acc[MT_M][MT_N];
#pragma unroll
    for (int i = 0; i < MT_M; ++i)
#pragma unroll
        for (int j = 0; j < MT_N; ++j) acc[i][j] = (f32x4){0.f, 0.f, 0.f, 0.f};

    const long rowA = ((long)m0 * ldA + (long)z * kOff) * 2;   // bytes
    const long rowB = ((long)n0 * ldB + (long)z * kOff) * 2;

    auto STAGE = [&](int buf, int k0) {
#pragma unroll
        for (int i = 0; i < BM / 64; ++i) {
            const int  L = i * 4096 + t * 16;
            const int  r = L >> 6, s = L & 63;
            const long gb = ((long)r * ldA + k0) * 2 + s;
            gld16((const char*)Ah + rowA + gb, (char*)&sAh[buf][0] + L);
        }
#pragma unroll
        for (int i = 0; i < BN / 64; ++i) {
            const int  L = i * 4096 + t * 16;
            const int  r = L >> 6, s = L & 63;
            const long gb = ((long)r * ldB + k0) * 2 + s;
            gld16((const char*)Bh + rowB + gb, (char*)&sBh[buf][0] + L);
            gld16((const char*)Bl + rowB + gb, (char*)&sBl[buf][0] + L);
        }
    };
    auto COMPUTE = [&](int buf) {
        bf16x8 ah[MT_M], bh[MT_N], bl[MT_N];
#pragma unroll
        for (int mt = 0; mt < MT_M; ++mt) {
            int row = wm * (BM / 2) + mt * 16 + lr;
            ah[mt] = *(const bf16x8*)&sAh[buf][row * 32 + ks * 8];
        }
#pragma unroll
        for (int nt = 0; nt < MT_N; ++nt) {
            int col = wn * (BN / 2) + nt * 16 + lr;
            bh[nt] = *(const bf16x8*)&sBh[buf][col * 32 + ks * 8];
            bl[nt] = *(const bf16x8*)&sBl[buf][col * 32 + ks * 8];
        }
#pragma unroll
        for (int mt = 0; mt < MT_M; ++mt)
#pragma unroll
            for (int nt = 0; nt < MT_N; ++nt) {
                acc[mt][nt] = __builtin_amdgcn_mfma_f32_16x16x32_bf16(
                    ah[mt], bh[nt], acc[mt][nt], 0, 0, 0);
                acc[mt][nt] = __builtin_amdgcn_mfma_f32_16x16x32_bf16(
                    ah[mt], bl[nt], acc[mt][nt], 0, 0, 0);
            }
    };

    if (DBUF) {
        STAGE(0, 0);
        __syncthreads();
        int cur = 0;
        for (int k0 = 0; k0 < Keff; k0 += 32) {
            if (k0 + 32 < Keff) STAGE(cur ^ 1, k0 + 32);
            COMPUTE(cur);
            __syncthreads();
            cur ^= 1;
        }
    } else {
        for (int k0 = 0; k0 < Keff; k0 += 32) {
            STAGE(0, k0);
            __syncthreads();
            COMPUTE(0);
            __syncthreads();
        }
    }

    const int rq = lane >> 4, cq = lane & 15;
#pragma unroll
    for (int mt = 0; mt < MT_M; ++mt)
#pragma unroll
        for (int nt = 0; nt < MT_N; ++nt) {
            int gr0 = m0 + wm * (BM / 2) + mt * 16 + rq * 4;
            int gc  = n0 + wn * (BN / 2) + nt * 16 + cq;
            float vv[4];
            float bv = (MODE == 5) ? 0.f : bias[gc];
#pragma unroll
            for (int i = 0; i < 4; ++i) {
                float v = acc[mt][nt][i] + bv;
                if (ACT == 1) v = fmaxf(v, 0.f);
                vv[i] = v;
            }
            if (MODE == 0 || MODE == 5) {
#pragma unroll
                for (int i = 0; i < 4; ++i)
                    C[(long)(gr0 + i) * ldc + gc + z * zC] = vv[i];
            } else if (MODE == 2) {
#pragma unroll
                for (int i = 0; i < 4; ++i) {
                    long off = (long)(gr0 + i) * ldc + gc;
                    short h = f2bf(vv[i]);
                    Ch[off] = h;
                    Cl[off] = f2bf(vv[i] - bf2f(h));
                }
            } else {               // MODE 3
                if ((int)z == vtZ) {
                    int b = gr0 >> 10, s0 = gr0 & (SEQ - 1);
                    int hh2 = gc >> 6, dk = gc & 63;
                    int swz = (((dk >> 1) & 3) << 3) | (((dk >> 3) & 1) << 5);
                    long base = (((long)(b * NHEAD + hh2)) * 64 + dk) * 1024
                              + (long)(((s0 & ~7) ^ swz) | (s0 & 7));
                    short4v hv, lv;
#pragma unroll
                    for (int i = 0; i < 4; ++i) {
                        short h = f2bf(vv[i]);
                        hv[i] = h;
                        lv[i] = f2bf(vv[i] - bf2f(h));
                    }
                    *(short4v*)&VTh[base] = hv;
                    *(short4v*)&VTl[base] = lv;
                } else {
                    float sc = ((int)z == scaledZ) ? 0.125f : 1.f;
#pragma unroll
                    for (int i = 0; i < 4; ++i) {
                        float v2 = vv[i] * sc;
                        int gr = gr0 + i;
                        int b = gr >> 10, s = gr & (SEQ - 1);
                        int hh2 = gc >> 6, dk = gc & 63;
                        int dks = dk ^ (((s >> 1) & 7) << 3);
                        long oidx = z * zC +
                            (((long)(b * NHEAD + hh2)) * SEQ + s) * 64 + dks;
                        short h = f2bf(v2);
                        Ch[oidx] = h;
                        Cl[oidx] = f2bf(v2 - bf2f(h));
                    }
                }
            }
        }
}

// ---------------- Qc combine: part0+part1+bias -> *0.125 -> MODE3 layout ----
__global__ __launch_bounds__(256) void qc_combine_kernel(
    const float* __restrict__ p0, const float* __restrict__ p1,
    const float* __restrict__ bias, short* __restrict__ Qh, short* __restrict__ Ql)
{
    long idx = (long)blockIdx.x * 256 + threadIdx.x;   // 262144 total
    int gr = (int)(idx >> 7);
    int gc4 = (int)(idx & 127) * 4;
    float4 a = *(const float4*)&p0[(long)gr * 512 + gc4];
    float4 b2 = *(const float4*)&p1[(long)gr * 512 + gc4];
    float4 bv = *(const float4*)&bias[gc4];
    float v[4] = {(a.x + b2.x + bv.x) * 0.125f, (a.y + b2.y + bv.y) * 0.125f,
                  (a.z + b2.z + bv.z) * 0.125f, (a.w + b2.w + bv.w) * 0.125f};
    int b = gr >> 10, s = gr & (SEQ - 1);
    int hh = gc4 >> 6, dk4 = gc4 & 63;
    int dks = dk4 ^ (((s >> 1) & 7) << 3);
    long o = (((long)(b * NHEAD + hh)) * SEQ + s) * 64 + dks;
    short4v hv, lv;
#pragma unroll
    for (int i = 0; i < 4; ++i) {
        short h = f2bf(v[i]);
        hv[i] = h;
        lv[i] = f2bf(v[i] - bf2f(h));
    }
    *(short4v*)&Qh[o] = hv;
    *(short4v*)&Ql[o] = lv;
}

// ---------------- fused attention: 32 q-rows, 2 waves, 2 blocks/CU ----------
template<bool CAUSAL>
__global__ __launch_bounds__(128) void attn_fused_kernel(
    const short* __restrict__ Qh, const short* __restrict__ Ql,
    const short* __restrict__ Kh, const short* __restrict__ Kl,
    const short* __restrict__ VTh, const short* __restrict__ VTl,
    float* __restrict__ attn, short* __restrict__ Oh, short* __restrict__ Ol)
{
    const int strip = blockIdx.x, bh = blockIdx.y;
    const int q0 = strip * 32;
    const int t = threadIdx.x, w = t >> 6, lane = t & 63;
    const int lr = lane & 15, ks = lane >> 4;
    const int rq = lane >> 4, cq = lane & 15;
    const int sxq = (lr >> 1) & 7;

    __shared__ short sKh[2][64*64], sKl[2][64*64];   // 32 KB
    __shared__ short sVh[2][64*64], sVl[2][64*64];   // 32 KB
    __shared__ short sPh[2][16*80], sPl[2][16*80];   // 10 KB

    const int diag  = strip >> 1;
    const int ktmax = CAUSAL ? diag + 1 : 16;

    {
        const long qb = ((long)bh * SEQ + q0) * 128;
#pragma unroll
        for (int i2 = 0; i2 < 2; ++i2) {
            int L = i2 * 2048 + t * 16; int r = L >> 7, off = L & 127;
            gld16((const char*)Qh + qb + (long)r*128 + off, (char*)&sVh[0][0] + L);
            gld16((const char*)Ql + qb + (long)r*128 + off, (char*)&sVl[0][0] + L);
        }
    }
    __syncthreads();
    bf16x8 qa[2][2];
#pragma unroll
    for (int k0 = 0; k0 < 2; ++k0) {
        int o = (w*16 + lr) * 64 + ((k0*32 + ks*8) ^ (sxq << 3));
        qa[k0][0] = *(const bf16x8*)&sVh[0][o];
        qa[k0][1] = *(const bf16x8*)&sVl[0][o];
    }
    __syncthreads();

    auto stageK = [&](int buf, int kt) {
        const long kb = ((long)bh * SEQ + kt*64) * 128;
#pragma unroll
        for (int i2 = 0; i2 < 4; ++i2) {
            int L = i2*2048 + t*16; int r = L >> 7, off = L & 127;
            gld16((const char*)Kh + kb + (long)r*128 + off, (char*)&sKh[buf][0] + L);
            gld16((const char*)Kl + kb + (long)r*128 + off, (char*)&sKl[buf][0] + L);
        }
    };
    auto stageV = [&](int buf, int kt) {
        const long vb = ((long)bh * 64) * 2048 + (long)kt * 128;
#pragma unroll
        for (int i2 = 0; i2 < 4; ++i2) {
            int L = i2*2048 + t*16; int r = L >> 7, off = L & 127;
            gld16((const char*)VTh + vb + (long)r*2048 + off, (char*)&sVh[buf][0] + L);
            gld16((const char*)VTl + vb + (long)r*2048 + off, (char*)&sVl[buf][0] + L);
        }
    };
    auto scoresOf = [&](int buf, int kt, f32x4* sc) {
#pragma unroll
        for (int nt = 0; nt < 4; ++nt) sc[nt] = (f32x4){0.f, 0.f, 0.f, 0.f};
#pragma unroll
        for (int k0 = 0; k0 < 2; ++k0) {
            bf16x8 kh[4], kl[4];
#pragma unroll
            for (int nt = 0; nt < 4; ++nt) {
                int o = (nt*16 + lr) * 64 + ((k0*32 + ks*8) ^ (sxq << 3));
                kh[nt] = *(const bf16x8*)&sKh[buf][o];
                kl[nt] = *(const bf16x8*)&sKl[buf][o];
            }
#pragma unroll
            for (int nt = 0; nt < 4; ++nt) {
                sc[nt] = __builtin_amdgcn_mfma_f32_16x16x32_bf16(
                    qa[k0][0], kh[nt], sc[nt], 0, 0, 0);
                sc[nt] = __builtin_amdgcn_mfma_f32_16x16x32_bf16(
                    qa[k0][0], kl[nt], sc[nt], 0, 0, 0);
                sc[nt] = __builtin_amdgcn_mfma_f32_16x16x32_bf16(
                    qa[k0][1], kh[nt], sc[nt], 0, 0, 0);
            }
        }
        if (CAUSAL && kt == diag) {
            int row = q0 + w*16 + rq*4;
#pragma unroll
            for (int nt = 0; nt < 4; ++nt) {
                int col = kt*64 + nt*16 + cq;
#pragma unroll
                for (int i = 0; i < 4; ++i)
                    if (col > row + i) sc[nt][i] = -1e9f;
            }
        }
    };

    // ---- pass 1: online max + sum ----
    float m[4]   = {-3e38f, -3e38f, -3e38f, -3e38f};
    float sum[4] = {0.f, 0.f, 0.f, 0.f};
    int cur = 0;
    stageK(0, 0);
    __syncthreads();
    for (int kt = 0; kt < ktmax; ++kt) {
        if (kt + 1 < ktmax) stageK(cur ^ 1, kt + 1);
        f32x4 sc[4];
        scoresOf(cur, kt, sc);
#pragma unroll
        for (int i = 0; i < 4; ++i) {
            float tm = fmaxf(fmaxf(sc[0][i], sc[1][i]), fmaxf(sc[2][i], sc[3][i]));
#pragma unroll
            for (int d2 = 1; d2 <= 8; d2 <<= 1) tm = fmaxf(tm, __shfl_xor(tm, d2, 64));
            float mn = fmaxf(m[i], tm);
            float ps = __expf(sc[0][i] - mn) + __expf(sc[1][i] - mn)
                     + __expf(sc[2][i] - mn) + __expf(sc[3][i] - mn);
#pragma unroll
            for (int d2 = 1; d2 <= 8; d2 <<= 1) ps += __shfl_xor(ps, d2, 64);
            sum[i] = sum[i] * __expf(m[i] - mn) + ps;
            m[i] = mn;
        }
        __syncthreads();
        cur ^= 1;
    }
    float inv[4];
#pragma unroll
    for (int i = 0; i < 4; ++i) inv[i] = 1.f / sum[i];

    // ---- pass 2: recompute, probs out, PV ----
    f32x4 acco[4];
#pragma unroll
    for (int nt = 0; nt < 4; ++nt) acco[nt] = (f32x4){0.f, 0.f, 0.f, 0.f};

    cur = 0;
    stageK(0, 0); stageV(0, 0);
    __syncthreads();
    for (int kt = 0; kt < 16; ++kt) {
        if (kt >= ktmax) {
#pragma unroll
            for (int nt = 0; nt < 4; ++nt)
#pragma unroll
                for (int i = 0; i < 4; ++i)
                    attn[((long)bh << 20) + ((long)(q0 + w*16 + rq*4 + i) << 10)
                         + kt*64 + nt*16 + cq] = 0.f;
            continue;
        }
        if (kt + 1 < ktmax) { stageK(cur ^ 1, kt + 1); stageV(cur ^ 1, kt + 1); }
        f32x4 sc[4];
        scoresOf(cur, kt, sc);
#pragma unroll
        for (int nt = 0; nt < 4; ++nt)
#pragma unroll
            for (int i = 0; i < 4; ++i) {
                float p = __expf(sc[nt][i] - m[i]) * inv[i];
                attn[((long)bh << 20) + ((long)(q0 + w*16 + rq*4 + i) << 10)
                     + kt*64 + nt*16 + cq] = p;
                short ph = f2bf(p);
                sPh[w][(rq*4 + i)*80 + nt*16 + cq] = ph;
                sPl[w][(rq*4 + i)*80 + nt*16 + cq] = f2bf(p - bf2f(ph));
            }
#pragma unroll
        for (int k0 = 0; k0 < 2; ++k0) {
            bf16x8 pah = *(const bf16x8*)&sPh[w][lr*80 + k0*32 + ks*8];
            bf16x8 pal = *(const bf16x8*)&sPl[w][lr*80 + k0*32 + ks*8];
#pragma unroll
            for (int nt = 0; nt < 4; ++nt) {
                int dk = nt*16 + lr;
                int swz = (((dk >> 1) & 3) << 3) | (((dk >> 3) & 1) << 5);
                int koff = (k0*32 + ks*8) ^ swz;
                bf16x8 vh8 = *(const bf16x8*)&sVh[cur][dk*64 + koff];
                bf16x8 vl8 = *(const bf16x8*)&sVl[cur][dk*64 + koff];
                acco[nt] = __builtin_amdgcn_mfma_f32_16x16x32_bf16(
                    pah, vh8, acco[nt], 0, 0, 0);
                acco[nt] = __builtin_amdgcn_mfma_f32_16x16x32_bf16(
                    pah, vl8, acco[nt], 0, 0, 0);
                acco[nt] = __builtin_amdgcn_mfma_f32_16x16x32_bf16(
                    pal, vh8, acco[nt], 0, 0, 0);
            }
        }
        __syncthreads();
        cur ^= 1;
    }

    const int b = bh >> 3, hh_ = bh & 7;
#pragma unroll
    for (int nt = 0; nt < 4; ++nt)
#pragma unroll
        for (int i = 0; i < 4; ++i) {
            float v = acco[nt][i];
            long oidx = ((long)(b * SEQ + q0 + w*16 + rq*4 + i)) * D_MODEL
                      + hh_*64 + nt*16 + cq;
            short h2 = f2bf(v);
            Oh[oidx] = h2;
            Ol[oidx] = f2bf(v - bf2f(h2));
        }
}

// ---------------- residual + NS partial slabs + bias + LayerNorm + hi/lo ----
template<int NS>
__global__ __launch_bounds__(256) void add_ln_kernel(
    const float* __restrict__ xin, const float* __restrict__ part, long PS,
    const float* __restrict__ bias,
    const float* __restrict__ g, const float* __restrict__ bb,
    float* __restrict__ xout, short* __restrict__ xh, short* __restrict__ xl)
{
    long row = blockIdx.x;
    const float* xr = xin + row * D_MODEL;
    float*       xo = xout+ row * D_MODEL;
    short*       hh = xh  + row * D_MODEL;
    short*       ll = xl  + row * D_MODEL;
    int t = threadIdx.x;

    float a0 = xr[t]       + bias[t];
    float a1 = xr[t + 256] + bias[t + 256];
#pragma unroll
    for (int s2 = 0; s2 < NS; ++s2) {
        a0 += part[s2 * PS + row * D_MODEL + t];
        a1 += part[s2 * PS + row * D_MODEL + t + 256];
    }

    float s = a0 + a1;
#pragma unroll
    for (int m = 32; m; m >>= 1) s += __shfl_xor(s, m, 64);
    __shared__ float red1[4];
    __shared__ float red2[4];
    int w = t >> 6, lane = t & 63;
    if (lane == 0) red1[w] = s;
    __syncthreads();
    float mean = (red1[0] + red1[1] + red1[2] + red1[3]) * (1.f / 512.f);

    float d0 = a0 - mean, d1 = a1 - mean;
    float q = d0 * d0 + d1 * d1;
#pragma unroll
    for (int m = 32; m; m >>= 1) q += __shfl_xor(q, m, 64);
    if (lane == 0) red2[w] = q;
    __syncthreads();
    float var  = (red2[0] + red2[1] + red2[2] + red2[3]) * (1.f / 512.f);
    float rstd = rsqrtf(var + 1e-5f);

    float r0 = d0 * rstd * g[t]       + bb[t];
    float r1 = d1 * rstd * g[t + 256] + bb[t + 256];
    xo[t] = r0; xo[t + 256] = r1;
    short h0 = f2bf(r0); hh[t] = h0;       ll[t] = f2bf(r0 - bf2f(h0));
    short h1 = f2bf(r1); hh[t + 256] = h1; ll[t + 256] = f2bf(r1 - bf2f(h1));
}

// ---------------------------------------------------------------------------
extern "C" void kernel_launch(void* const* d_in, const int* in_sizes, int n_in,
                              void* d_out, int out_size, void* d_ws, size_t ws_size,
                              hipStream_t stream)
{
    const int*   tokens = (const int*)  d_in[0];
    const float* enc    = (const float*)d_in[1];
    const float* emb    = (const float*)d_in[3];
    const float* Wqkvo  = (const float*)d_in[4];   // [L,2,4,D,D]
    const float* bqkvo  = (const float*)d_in[5];   // [L,2,4,D]
    const float* W1     = (const float*)d_in[6];   // [L,D,DFF]
    const float* b1     = (const float*)d_in[7];
    const float* W2     = (const float*)d_in[8];   // [L,DFF,D]
    const float* b2     = (const float*)d_in[9];
    const float* lng    = (const float*)d_in[10];  // [L,3,D]
    const float* lnb    = (const float*)d_in[11];
    const float* Wout   = (const float*)d_in[12];  // [D,V]
    const float* bout   = (const float*)d_in[13];

    float* out    = (float*)d_out;
    float* selfA  = out + 65536000L;
    float* crossA = selfA + 67108864L;

    // workspace carve (~112 MB)
    char* p = (char*)d_ws;
    auto carve = [&](size_t bytes) { char* r = p; p += (bytes + 255) & ~255UL; return r; };
    float* x      = (float*)carve(1048576L * 4);
    short* xh     = (short*)carve(1048576L * 2);
    short* xl     = (short*)carve(1048576L * 2);
    short* ench   = (short*)carve(1048576L * 2);
    short* encl   = (short*)carve(1048576L * 2);
    short* qh     = (short*)carve(2097152L * 2);   // head-major Q|K hi
    short* ql     = (short*)carve(2097152L * 2);   // head-major Q|K lo
    short* vth    = (short*)carve(1048576L * 2);   // transposed V hi
    short* vtl    = (short*)carve(1048576L * 2);
    short* oh     = (short*)carve(1048576L * 2);
    short* ol     = (short*)carve(1048576L * 2);
    short* t1h    = (short*)carve(4194304L * 2);   // FFN1 out hi
    short* t1l    = (short*)carve(4194304L * 2);
    float* part   = (float*)carve(4L * PSLAB * 4); // 4 K-split slabs
    short* WTLh   = (short*)carve(4194304L * 2);   // per-layer weights T hi
    short* WTLl   = (short*)carve(4194304L * 2);
    short* WTh    = (short*)carve(8192000L * 2);   // vocab chunk T hi
    short* WTl    = (short*)carve(8192000L * 2);

    const long PW = 262144L;    // 512*512
    const long HS = 1048576L;   // per attention operand slab

    embed_pe_kernel<<<4096, 256, 0, stream>>>(tokens, emb, x, xh, xl);
    cvt_kernel<<<1024, 256, 0, stream>>>(enc, ench, encl);

    for (int l = 0; l < NLAYER; ++l) {
        const float* bl = bqkvo + (long)l * 4096L;
        const float* bc = bl + 2048;
        const float* g  = lng + (long)l * 3 * 512;
        const float* bb = lnb + (long)l * 3 * 512;

        wtrans_layer_kernel<<<1024, 256, 0, stream>>>(Wqkvo, W1, W2, l, WTLh, WTLl);

        // ---- self-attention ----
        gemm_mfma_kernel<64,64,0,3,true><<<dim3(8, 32, 3), 256, 0, stream>>>(
            xh, WTLh, WTLl, bl, nullptr, qh, ql, vth, vtl,
            512, 512, 512, 0, PW, 512, HS, 0, /*scaledZ=*/0, /*vtZ=*/2);
        attn_fused_kernel<true><<<dim3(32, 16), 128, 0, stream>>>(
            qh, ql, qh + HS, ql + HS, vth, vtl,
            selfA + (long)l * 16777216L, oh, ol);
        gemm_mfma_kernel<64,64,0,5,true><<<dim3(8, 32, 2), 256, 0, stream>>>(
            oh, WTLh + 3*PW, WTLl + 3*PW, nullptr, part, nullptr, nullptr,
            nullptr, nullptr, 256, 512, 512, 512, 0, 0, PSLAB, 256, -1, -1);
        add_ln_kernel<2><<<MROWS, 256, 0, stream>>>(
            x, part, PSLAB, bl + 3*512, g, bb, x, xh, xl);

        // ---- cross-attention ----
        gemm_mfma_kernel<64,64,0,5,true><<<dim3(8, 32, 2), 256, 0, stream>>>(
            xh, WTLh + 4*PW, WTLl + 4*PW, nullptr, part, nullptr, nullptr,
            nullptr, nullptr, 256, 512, 512, 512, 0, 0, PSLAB, 256, -1, -1);
        qc_combine_kernel<<<1024, 256, 0, stream>>>(part, part + PSLAB, bc, qh, ql);
        gemm_mfma_kernel<64,64,0,3,true><<<dim3(8, 32, 2), 256, 0, stream>>>(
            ench, WTLh + 5*PW, WTLl + 5*PW, bc + 512, nullptr,
            qh + HS, ql + HS, vth, vtl,
            512, 512, 512, 0, PW, 512, HS, 0, /*scaledZ=*/-1, /*vtZ=*/1);
        attn_fused_kernel<false><<<dim3(32, 16), 128, 0, stream>>>(
            qh, ql, qh + HS, ql + HS, vth, vtl,
            crossA + (long)l * 16777216L, oh, ol);
        gemm_mfma_kernel<64,64,0,5,true><<<dim3(8, 32, 2), 256, 0, stream>>>(
            oh, WTLh + 7*PW, WTLl + 7*PW, nullptr, part, nullptr, nullptr,
            nullptr, nullptr, 256, 512, 512, 512, 0, 0, PSLAB, 256, -1, -1);
        add_ln_kernel<2><<<MROWS, 256, 0, stream>>>(
            x, part, PSLAB, bc + 3*512, g + 512, bb + 512, x, xh, xl);

        // ---- FFN ----
        gemm_mfma_kernel<64,64,1,2,true><<<dim3(32, 32, 1), 256, 0, stream>>>(
            xh, WTLh + 2097152L, WTLl + 2097152L, b1 + (long)l * 2048,
            nullptr, t1h, t1l, nullptr, nullptr,
            512, 512, 512, 2048, 0, 0, 0, 0, -1, -1);
        gemm_mfma_kernel<64,64,0,5,true><<<dim3(8, 32, 4), 256, 0, stream>>>(
            t1h, WTLh + 3145728L, WTLl + 3145728L, nullptr, part,
            nullptr, nullptr, nullptr, nullptr,
            512, 2048, 2048, 512, 0, 0, PSLAB, 512, -1, -1);
        add_ln_kernel<4><<<MROWS, 256, 0, stream>>>(
            x, part, PSLAB, b2 + (long)l * 512, g + 1024, bb + 1024, x, xh, xl);
    }

    // ---- final vocab projection, two 16000-wide chunks ----
    for (int c = 0; c < 2; ++c) {
        wtrans_kernel<<<dim3(250, 8, 1), 256, 0, stream>>>(
            Wout + c * 16000, WTh, WTl, 512, VOCAB);
        gemm_mfma_kernel<128,128,0,0,true><<<dim3(125, 16, 1), 256, 0, stream>>>(
            xh, WTh, WTl, bout + c * 16000, out + c * 16000,
            nullptr, nullptr, nullptr, nullptr,
            512, 512, 512, VOCAB, 0, 0, 0, 0, -1, -1);
    }
}

// Round 13
// 1070.582 us; speedup vs baseline: 1.3529x; 1.1777x over previous
//
#include <hip/hip_runtime.h>
#include <hip/hip_bf16.h>

// ---------------------------------------------------------------------------
// Transformer decoder, fp32 I/O. GEMMs: pure bf16 1-product (Ah@Bh^T), fp32
// accumulate. Attention internals keep full split-bf16 3-product hi/lo.
// R11/R12 schedule: 64^2 dbuf in-layer, 128^2 dbuf vocab.
// B=2, ST=SS=1024, D=512, H=8, DK=64, L=4, DFF=2048, V=32000.
// ---------------------------------------------------------------------------

#define D_MODEL 512
#define NHEAD   8
#define DKH     64
#define SEQ     1024
#define NLAYER  4
#define DFF_    2048
#define VOCAB   32000
#define BATCH   2
#define MROWS   (BATCH*SEQ)   // 2048
#define PSLAB   1048576L

typedef short bf16x8 __attribute__((ext_vector_type(8)));
typedef short short4v __attribute__((ext_vector_type(4)));
typedef float f32x4  __attribute__((ext_vector_type(4)));

static __device__ __forceinline__ short f2bf(float f) {
    __hip_bfloat16 h = __float2bfloat16(f);
    return *reinterpret_cast<short*>(&h);
}
static __device__ __forceinline__ float bf2f(short s) {
    __hip_bfloat16 h = *reinterpret_cast<__hip_bfloat16*>(&s);
    return __bfloat162float(h);
}
static __device__ __forceinline__ void gld16(const void* g, void* l) {
    __builtin_amdgcn_global_load_lds(
        (__attribute__((address_space(1))) void*)(void*)g,
        (__attribute__((address_space(3))) void*)l, 16, 0, 0);
}

// ---------------- embedding + positional encoding + hi ----------------------
__global__ __launch_bounds__(256) void embed_pe_kernel(
    const int* __restrict__ tokens, const float* __restrict__ emb,
    float* __restrict__ x, short* __restrict__ xh)
{
    long idx = (long)blockIdx.x * 256 + threadIdx.x;   // over 1,048,576
    int  d   = (int)(idx & (D_MODEL - 1));
    long row = idx >> 9;
    int  s   = (int)(row & (SEQ - 1));
    int  tok = tokens[row];
    float twoi = (float)((d >> 1) << 1);
    float div  = expf(twoi * (-9.210340371976184f / 512.0f));
    float arg  = (float)s * div;
    float pe   = (d & 1) ? cosf(arg) : sinf(arg);
    float v = emb[(long)tok * D_MODEL + d] * 22.62741699796952f + pe; // sqrt(512)
    x[idx] = v;
    xh[idx] = f2bf(v);
}

// ---------------- fp32 -> bf16 hi -------------------------------------------
__global__ __launch_bounds__(256) void cvt_kernel(
    const float* __restrict__ in, short* __restrict__ h)
{
    long e = ((long)blockIdx.x * 256 + threadIdx.x) * 4;
    float4 v = *(const float4*)&in[e];
    short4v hv;
    hv[0] = f2bf(v.x); hv[1] = f2bf(v.y); hv[2] = f2bf(v.z); hv[3] = f2bf(v.w);
    *(short4v*)&h[e] = hv;
}

// ---------------- weight transpose-convert: W[K,N] -> WT[N,K] hi ------------
__global__ __launch_bounds__(256) void wtrans_kernel(
    const float* __restrict__ W, short* __restrict__ Th,
    int K, int ldW)
{
    const int n0 = blockIdx.x * 64, k0 = blockIdx.y * 64;
    __shared__ float tile[64][65];
    const int t = threadIdx.x;
#pragma unroll
    for (int i = 0; i < 4; ++i) {
        int e = t + i * 256; int kk = e >> 4; int nn = (e & 15) * 4;
        float4 v = *(const float4*)&W[(long)(k0 + kk) * ldW + n0 + nn];
        tile[kk][nn] = v.x; tile[kk][nn + 1] = v.y;
        tile[kk][nn + 2] = v.z; tile[kk][nn + 3] = v.w;
    }
    __syncthreads();
    const int n = t >> 2, ks = (t & 3) * 16;
    short h8[16];
#pragma unroll
    for (int j = 0; j < 16; ++j) h8[j] = f2bf(tile[ks + j][n]);
    long base = (long)(n0 + n) * K + k0 + ks;
    *(bf16x8*)&Th[base]     = *(bf16x8*)&h8[0];
    *(bf16x8*)&Th[base + 8] = *(bf16x8*)&h8[8];
}

// ---------------- merged per-layer weight transpose (10 matrices, hi only) --
__global__ __launch_bounds__(256) void wtrans_layer_kernel(
    const float* __restrict__ Wqkvo, const float* __restrict__ W1,
    const float* __restrict__ W2, int l,
    short* __restrict__ Th)
{
    const int j = blockIdx.x;
    const float* W; int ldW, K; long dstOff; int n0, k0;
    if (j < 512) {
        int mat = j >> 6, tile_ = j & 63;
        W = Wqkvo + (long)l * 2097152L + (long)mat * 262144L;
        ldW = 512; K = 512; dstOff = (long)mat * 262144L;
        n0 = (tile_ & 7) * 64; k0 = (tile_ >> 3) * 64;
    } else if (j < 768) {
        int t2 = j - 512;
        W = W1 + (long)l * 1048576L; ldW = 2048; K = 512; dstOff = 2097152L;
        n0 = (t2 & 31) * 64; k0 = (t2 >> 5) * 64;
    } else {
        int t3 = j - 768;
        W = W2 + (long)l * 1048576L; ldW = 512; K = 2048; dstOff = 3145728L;
        n0 = (t3 & 7) * 64; k0 = (t3 >> 3) * 64;
    }
    __shared__ float tile[64][65];
    const int t = threadIdx.x;
#pragma unroll
    for (int i = 0; i < 4; ++i) {
        int e = t + i * 256; int kk = e >> 4; int nn = (e & 15) * 4;
        float4 v = *(const float4*)&W[(long)(k0 + kk) * ldW + n0 + nn];
        tile[kk][nn] = v.x; tile[kk][nn + 1] = v.y;
        tile[kk][nn + 2] = v.z; tile[kk][nn + 3] = v.w;
    }
    __syncthreads();
    const int n = t >> 2, ks = (t & 3) * 16;
    short h8[16];
#pragma unroll
    for (int j2 = 0; j2 < 16; ++j2) h8[j2] = f2bf(tile[ks + j2][n]);
    long base = dstOff + (long)(n0 + n) * K + k0 + ks;
    *(bf16x8*)&Th[base]     = *(bf16x8*)&h8[0];
    *(bf16x8*)&Th[base + 8] = *(bf16x8*)&h8[8];
}

// ---------------- 1-product MFMA GEMM: C = act(Ah@Bh^T + bias) --------------
// K-window at z*kOff. MODE 0: fp32+bias. MODE 2: bf16 hi+bias(+relu).
// MODE 3: head-major attn operand hi/lo w/ dk swizzle (z==vtZ -> transposed V;
// z==scaledZ -> *0.125). MODE 5: fp32 partial, no bias.
// DBUF: double-buffered LDS, STAGE(k+1) before compute(k), 1 barrier/K-step.
template<int BM, int BN, int ACT, int MODE, bool DBUF>
__global__ __launch_bounds__(256) void gemm_mfma_kernel(
    const short* __restrict__ Ah, const short* __restrict__ Bh,
    const float* __restrict__ bias, float* __restrict__ C,
    short* __restrict__ Ch, short* __restrict__ Cl,
    short* __restrict__ VTh, short* __restrict__ VTl,
    int Keff, int ldA, int ldB, int ldc,
    long zB, long zBias, long zC, int kOff, int scaledZ, int vtZ)
{
    constexpr int NB   = DBUF ? 2 : 1;
    constexpr int MT_M = BM / 32;
    constexpr int MT_N = BN / 32;
    const long z = blockIdx.z;
    Bh += z * zB;
    if (MODE != 5) bias += z * zBias;

    const int n0 = blockIdx.x * BN, m0 = blockIdx.y * BM;
    const int t = threadIdx.x;
    const int w = t >> 6, lane = t & 63;
    const int wm = w >> 1, wn = w & 1;
    const int lr = lane & 15, ks = lane >> 4;

    __shared__ short sAh[NB][BM * 32];
    __shared__ short sBh[NB][BN * 32];

    f32x4 acc[MT_M][MT_N];
#pragma unroll
    for (int i = 0; i < MT_M; ++i)
#pragma unroll
        for (int j = 0; j < MT_N; ++j) acc[i][j] = (f32x4){0.f, 0.f, 0.f, 0.f};

    const long rowA = ((long)m0 * ldA + (long)z * kOff) * 2;   // bytes
    const long rowB = ((long)n0 * ldB + (long)z * kOff) * 2;

    auto STAGE = [&](int buf, int k0) {
#pragma unroll
        for (int i = 0; i < BM / 64; ++i) {
            const int  L = i * 4096 + t * 16;
            const int  r = L >> 6, s = L & 63;
            const long gb = ((long)r * ldA + k0) * 2 + s;
            gld16((const char*)Ah + rowA + gb, (char*)&sAh[buf][0] + L);
        }
#pragma unroll
        for (int i = 0; i < BN / 64; ++i) {
            const int  L = i * 4096 + t * 16;
            const int  r = L >> 6, s = L & 63;
            const long gb = ((long)r * ldB + k0) * 2 + s;
            gld16((const char*)Bh + rowB + gb, (char*)&sBh[buf][0] + L);
        }
    };
    auto COMPUTE = [&](int buf) {
        bf16x8 ah[MT_M], bh[MT_N];
#pragma unroll
        for (int mt = 0; mt < MT_M; ++mt) {
            int row = wm * (BM / 2) + mt * 16 + lr;
            ah[mt] = *(const bf16x8*)&sAh[buf][row * 32 + ks * 8];
        }
#pragma unroll
        for (int nt = 0; nt < MT_N; ++nt) {
            int col = wn * (BN / 2) + nt * 16 + lr;
            bh[nt] = *(const bf16x8*)&sBh[buf][col * 32 + ks * 8];
        }
#pragma unroll
        for (int mt = 0; mt < MT_M; ++mt)
#pragma unroll
            for (int nt = 0; nt < MT_N; ++nt)
                acc[mt][nt] = __builtin_amdgcn_mfma_f32_16x16x32_bf16(
                    ah[mt], bh[nt], acc[mt][nt], 0, 0, 0);
    };

    if (DBUF) {
        STAGE(0, 0);
        __syncthreads();
        int cur = 0;
        for (int k0 = 0; k0 < Keff; k0 += 32) {
            if (k0 + 32 < Keff) STAGE(cur ^ 1, k0 + 32);
            COMPUTE(cur);
            __syncthreads();
            cur ^= 1;
        }
    } else {
        for (int k0 = 0; k0 < Keff; k0 += 32) {
            STAGE(0, k0);
            __syncthreads();
            COMPUTE(0);
            __syncthreads();
        }
    }

    const int rq = lane >> 4, cq = lane & 15;
#pragma unroll
    for (int mt = 0; mt < MT_M; ++mt)
#pragma unroll
        for (int nt = 0; nt < MT_N; ++nt) {
            int gr0 = m0 + wm * (BM / 2) + mt * 16 + rq * 4;
            int gc  = n0 + wn * (BN / 2) + nt * 16 + cq;
            float vv[4];
            float bv = (MODE == 5) ? 0.f : bias[gc];
#pragma unroll
            for (int i = 0; i < 4; ++i) {
                float v = acc[mt][nt][i] + bv;
                if (ACT == 1) v = fmaxf(v, 0.f);
                vv[i] = v;
            }
            if (MODE == 0 || MODE == 5) {
#pragma unroll
                for (int i = 0; i < 4; ++i)
                    C[(long)(gr0 + i) * ldc + gc + z * zC] = vv[i];
            } else if (MODE == 2) {
#pragma unroll
                for (int i = 0; i < 4; ++i)
                    Ch[(long)(gr0 + i) * ldc + gc] = f2bf(vv[i]);
            } else {               // MODE 3
                if ((int)z == vtZ) {
                    int b = gr0 >> 10, s0 = gr0 & (SEQ - 1);
                    int hh2 = gc >> 6, dk = gc & 63;
                    int swz = (((dk >> 1) & 3) << 3) | (((dk >> 3) & 1) << 5);
                    long base = (((long)(b * NHEAD + hh2)) * 64 + dk) * 1024
                              + (long)(((s0 & ~7) ^ swz) | (s0 & 7));
                    short4v hv, lv;
#pragma unroll
                    for (int i = 0; i < 4; ++i) {
                        short h = f2bf(vv[i]);
                        hv[i] = h;
                        lv[i] = f2bf(vv[i] - bf2f(h));
                    }
                    *(short4v*)&VTh[base] = hv;
                    *(short4v*)&VTl[base] = lv;
                } else {
                    float sc = ((int)z == scaledZ) ? 0.125f : 1.f;
#pragma unroll
                    for (int i = 0; i < 4; ++i) {
                        float v2 = vv[i] * sc;
                        int gr = gr0 + i;
                        int b = gr >> 10, s = gr & (SEQ - 1);
                        int hh2 = gc >> 6, dk = gc & 63;
                        int dks = dk ^ (((s >> 1) & 7) << 3);
                        long oidx = z * zC +
                            (((long)(b * NHEAD + hh2)) * SEQ + s) * 64 + dks;
                        short h = f2bf(v2);
                        Ch[oidx] = h;
                        Cl[oidx] = f2bf(v2 - bf2f(h));
                    }
                }
            }
        }
}

// ---------------- Qc combine: part0+part1+bias -> *0.125 -> MODE3 layout ----
__global__ __launch_bounds__(256) void qc_combine_kernel(
    const float* __restrict__ p0, const float* __restrict__ p1,
    const float* __restrict__ bias, short* __restrict__ Qh, short* __restrict__ Ql)
{
    long idx = (long)blockIdx.x * 256 + threadIdx.x;   // 262144 total
    int gr = (int)(idx >> 7);
    int gc4 = (int)(idx & 127) * 4;
    float4 a = *(const float4*)&p0[(long)gr * 512 + gc4];
    float4 b2 = *(const float4*)&p1[(long)gr * 512 + gc4];
    float4 bv = *(const float4*)&bias[gc4];
    float v[4] = {(a.x + b2.x + bv.x) * 0.125f, (a.y + b2.y + bv.y) * 0.125f,
                  (a.z + b2.z + bv.z) * 0.125f, (a.w + b2.w + bv.w) * 0.125f};
    int b = gr >> 10, s = gr & (SEQ - 1);
    int hh = gc4 >> 6, dk4 = gc4 & 63;
    int dks = dk4 ^ (((s >> 1) & 7) << 3);
    long o = (((long)(b * NHEAD + hh)) * SEQ + s) * 64 + dks;
    short4v hv, lv;
#pragma unroll
    for (int i = 0; i < 4; ++i) {
        short h = f2bf(v[i]);
        hv[i] = h;
        lv[i] = f2bf(v[i] - bf2f(h));
    }
    *(short4v*)&Qh[o] = hv;
    *(short4v*)&Ql[o] = lv;
}

// ---------------- fused attention: 32 q-rows, 2 waves, 2 blocks/CU ----------
// (full 3-product hi/lo internals; O written hi-only — O-proj is 1-product)
template<bool CAUSAL>
__global__ __launch_bounds__(128) void attn_fused_kernel(
    const short* __restrict__ Qh, const short* __restrict__ Ql,
    const short* __restrict__ Kh, const short* __restrict__ Kl,
    const short* __restrict__ VTh, const short* __restrict__ VTl,
    float* __restrict__ attn, short* __restrict__ Oh)
{
    const int strip = blockIdx.x, bh = blockIdx.y;
    const int q0 = strip * 32;
    const int t = threadIdx.x, w = t >> 6, lane = t & 63;
    const int lr = lane & 15, ks = lane >> 4;
    const int rq = lane >> 4, cq = lane & 15;
    const int sxq = (lr >> 1) & 7;

    __shared__ short sKh[2][64*64], sKl[2][64*64];   // 32 KB
    __shared__ short sVh[2][64*64], sVl[2][64*64];   // 32 KB
    __shared__ short sPh[2][16*80], sPl[2][16*80];   // 10 KB

    const int diag  = strip >> 1;
    const int ktmax = CAUSAL ? diag + 1 : 16;

    {
        const long qb = ((long)bh * SEQ + q0) * 128;
#pragma unroll
        for (int i2 = 0; i2 < 2; ++i2) {
            int L = i2 * 2048 + t * 16; int r = L >> 7, off = L & 127;
            gld16((const char*)Qh + qb + (long)r*128 + off, (char*)&sVh[0][0] + L);
            gld16((const char*)Ql + qb + (long)r*128 + off, (char*)&sVl[0][0] + L);
        }
    }
    __syncthreads();
    bf16x8 qa[2][2];
#pragma unroll
    for (int k0 = 0; k0 < 2; ++k0) {
        int o = (w*16 + lr) * 64 + ((k0*32 + ks*8) ^ (sxq << 3));
        qa[k0][0] = *(const bf16x8*)&sVh[0][o];
        qa[k0][1] = *(const bf16x8*)&sVl[0][o];
    }
    __syncthreads();

    auto stageK = [&](int buf, int kt) {
        const long kb = ((long)bh * SEQ + kt*64) * 128;
#pragma unroll
        for (int i2 = 0; i2 < 4; ++i2) {
            int L = i2*2048 + t*16; int r = L >> 7, off = L & 127;
            gld16((const char*)Kh + kb + (long)r*128 + off, (char*)&sKh[buf][0] + L);
            gld16((const char*)Kl + kb + (long)r*128 + off, (char*)&sKl[buf][0] + L);
        }
    };
    auto stageV = [&](int buf, int kt) {
        const long vb = ((long)bh * 64) * 2048 + (long)kt * 128;
#pragma unroll
        for (int i2 = 0; i2 < 4; ++i2) {
            int L = i2*2048 + t*16; int r = L >> 7, off = L & 127;
            gld16((const char*)VTh + vb + (long)r*2048 + off, (char*)&sVh[buf][0] + L);
            gld16((const char*)VTl + vb + (long)r*2048 + off, (char*)&sVl[buf][0] + L);
        }
    };
    auto scoresOf = [&](int buf, int kt, f32x4* sc) {
#pragma unroll
        for (int nt = 0; nt < 4; ++nt) sc[nt] = (f32x4){0.f, 0.f, 0.f, 0.f};
#pragma unroll
        for (int k0 = 0; k0 < 2; ++k0) {
            bf16x8 kh[4], kl[4];
#pragma unroll
            for (int nt = 0; nt < 4; ++nt) {
                int o = (nt*16 + lr) * 64 + ((k0*32 + ks*8) ^ (sxq << 3));
                kh[nt] = *(const bf16x8*)&sKh[buf][o];
                kl[nt] = *(const bf16x8*)&sKl[buf][o];
            }
#pragma unroll
            for (int nt = 0; nt < 4; ++nt) {
                sc[nt] = __builtin_amdgcn_mfma_f32_16x16x32_bf16(
                    qa[k0][0], kh[nt], sc[nt], 0, 0, 0);
                sc[nt] = __builtin_amdgcn_mfma_f32_16x16x32_bf16(
                    qa[k0][0], kl[nt], sc[nt], 0, 0, 0);
                sc[nt] = __builtin_amdgcn_mfma_f32_16x16x32_bf16(
                    qa[k0][1], kh[nt], sc[nt], 0, 0, 0);
            }
        }
        if (CAUSAL && kt == diag) {
            int row = q0 + w*16 + rq*4;
#pragma unroll
            for (int nt = 0; nt < 4; ++nt) {
                int col = kt*64 + nt*16 + cq;
#pragma unroll
                for (int i = 0; i < 4; ++i)
                    if (col > row + i) sc[nt][i] = -1e9f;
            }
        }
    };

    // ---- pass 1: online max + sum ----
    float m[4]   = {-3e38f, -3e38f, -3e38f, -3e38f};
    float sum[4] = {0.f, 0.f, 0.f, 0.f};
    int cur = 0;
    stageK(0, 0);
    __syncthreads();
    for (int kt = 0; kt < ktmax; ++kt) {
        if (kt + 1 < ktmax) stageK(cur ^ 1, kt + 1);
        f32x4 sc[4];
        scoresOf(cur, kt, sc);
#pragma unroll
        for (int i = 0; i < 4; ++i) {
            float tm = fmaxf(fmaxf(sc[0][i], sc[1][i]), fmaxf(sc[2][i], sc[3][i]));
#pragma unroll
            for (int d2 = 1; d2 <= 8; d2 <<= 1) tm = fmaxf(tm, __shfl_xor(tm, d2, 64));
            float mn = fmaxf(m[i], tm);
            float ps = __expf(sc[0][i] - mn) + __expf(sc[1][i] - mn)
                     + __expf(sc[2][i] - mn) + __expf(sc[3][i] - mn);
#pragma unroll
            for (int d2 = 1; d2 <= 8; d2 <<= 1) ps += __shfl_xor(ps, d2, 64);
            sum[i] = sum[i] * __expf(m[i] - mn) + ps;
            m[i] = mn;
        }
        __syncthreads();
        cur ^= 1;
    }
    float inv[4];
#pragma unroll
    for (int i = 0; i < 4; ++i) inv[i] = 1.f / sum[i];

    // ---- pass 2: recompute, probs out, PV ----
    f32x4 acco[4];
#pragma unroll
    for (int nt = 0; nt < 4; ++nt) acco[nt] = (f32x4){0.f, 0.f, 0.f, 0.f};

    cur = 0;
    stageK(0, 0); stageV(0, 0);
    __syncthreads();
    for (int kt = 0; kt < 16; ++kt) {
        if (kt >= ktmax) {
#pragma unroll
            for (int nt = 0; nt < 4; ++nt)
#pragma unroll
                for (int i = 0; i < 4; ++i)
                    attn[((long)bh << 20) + ((long)(q0 + w*16 + rq*4 + i) << 10)
                         + kt*64 + nt*16 + cq] = 0.f;
            continue;
        }
        if (kt + 1 < ktmax) { stageK(cur ^ 1, kt + 1); stageV(cur ^ 1, kt + 1); }
        f32x4 sc[4];
        scoresOf(cur, kt, sc);
#pragma unroll
        for (int nt = 0; nt < 4; ++nt)
#pragma unroll
            for (int i = 0; i < 4; ++i) {
                float p = __expf(sc[nt][i] - m[i]) * inv[i];
                attn[((long)bh << 20) + ((long)(q0 + w*16 + rq*4 + i) << 10)
                     + kt*64 + nt*16 + cq] = p;
                short ph = f2bf(p);
                sPh[w][(rq*4 + i)*80 + nt*16 + cq] = ph;
                sPl[w][(rq*4 + i)*80 + nt*16 + cq] = f2bf(p - bf2f(ph));
            }
#pragma unroll
        for (int k0 = 0; k0 < 2; ++k0) {
            bf16x8 pah = *(const bf16x8*)&sPh[w][lr*80 + k0*32 + ks*8];
            bf16x8 pal = *(const bf16x8*)&sPl[w][lr*80 + k0*32 + ks*8];
#pragma unroll
            for (int nt = 0; nt < 4; ++nt) {
                int dk = nt*16 + lr;
                int swz = (((dk >> 1) & 3) << 3) | (((dk >> 3) & 1) << 5);
                int koff = (k0*32 + ks*8) ^ swz;
                bf16x8 vh8 = *(const bf16x8*)&sVh[cur][dk*64 + koff];
                bf16x8 vl8 = *(const bf16x8*)&sVl[cur][dk*64 + koff];
                acco[nt] = __builtin_amdgcn_mfma_f32_16x16x32_bf16(
                    pah, vh8, acco[nt], 0, 0, 0);
                acco[nt] = __builtin_amdgcn_mfma_f32_16x16x32_bf16(
                    pah, vl8, acco[nt], 0, 0, 0);
                acco[nt] = __builtin_amdgcn_mfma_f32_16x16x32_bf16(
                    pal, vh8, acco[nt], 0, 0, 0);
            }
        }
        __syncthreads();
        cur ^= 1;
    }

    const int b = bh >> 3, hh_ = bh & 7;
#pragma unroll
    for (int nt = 0; nt < 4; ++nt)
#pragma unroll
        for (int i = 0; i < 4; ++i) {
            long oidx = ((long)(b * SEQ + q0 + w*16 + rq*4 + i)) * D_MODEL
                      + hh_*64 + nt*16 + cq;
            Oh[oidx] = f2bf(acco[nt][i]);
        }
}

// ---------------- residual + NS partial slabs + bias + LayerNorm + hi -------
template<int NS>
__global__ __launch_bounds__(256) void add_ln_kernel(
    const float* __restrict__ xin, const float* __restrict__ part, long PS,
    const float* __restrict__ bias,
    const float* __restrict__ g, const float* __restrict__ bb,
    float* __restrict__ xout, short* __restrict__ xh)
{
    long row = blockIdx.x;
    const float* xr = xin + row * D_MODEL;
    float*       xo = xout+ row * D_MODEL;
    short*       hh = xh  + row * D_MODEL;
    int t = threadIdx.x;

    float a0 = xr[t]       + bias[t];
    float a1 = xr[t + 256] + bias[t + 256];
#pragma unroll
    for (int s2 = 0; s2 < NS; ++s2) {
        a0 += part[s2 * PS + row * D_MODEL + t];
        a1 += part[s2 * PS + row * D_MODEL + t + 256];
    }

    float s = a0 + a1;
#pragma unroll
    for (int m = 32; m; m >>= 1) s += __shfl_xor(s, m, 64);
    __shared__ float red1[4];
    __shared__ float red2[4];
    int w = t >> 6, lane = t & 63;
    if (lane == 0) red1[w] = s;
    __syncthreads();
    float mean = (red1[0] + red1[1] + red1[2] + red1[3]) * (1.f / 512.f);

    float d0 = a0 - mean, d1 = a1 - mean;
    float q = d0 * d0 + d1 * d1;
#pragma unroll
    for (int m = 32; m; m >>= 1) q += __shfl_xor(q, m, 64);
    if (lane == 0) red2[w] = q;
    __syncthreads();
    float var  = (red2[0] + red2[1] + red2[2] + red2[3]) * (1.f / 512.f);
    float rstd = rsqrtf(var + 1e-5f);

    float r0 = d0 * rstd * g[t]       + bb[t];
    float r1 = d1 * rstd * g[t + 256] + bb[t + 256];
    xo[t] = r0; xo[t + 256] = r1;
    hh[t] = f2bf(r0);
    hh[t + 256] = f2bf(r1);
}

// ---------------------------------------------------------------------------
extern "C" void kernel_launch(void* const* d_in, const int* in_sizes, int n_in,
                              void* d_out, int out_size, void* d_ws, size_t ws_size,
                              hipStream_t stream)
{
    const int*   tokens = (const int*)  d_in[0];
    const float* enc    = (const float*)d_in[1];
    const float* emb    = (const float*)d_in[3];
    const float* Wqkvo  = (const float*)d_in[4];   // [L,2,4,D,D]
    const float* bqkvo  = (const float*)d_in[5];   // [L,2,4,D]
    const float* W1     = (const float*)d_in[6];   // [L,D,DFF]
    const float* b1     = (const float*)d_in[7];
    const float* W2     = (const float*)d_in[8];   // [L,DFF,D]
    const float* b2     = (const float*)d_in[9];
    const float* lng    = (const float*)d_in[10];  // [L,3,D]
    const float* lnb    = (const float*)d_in[11];
    const float* Wout   = (const float*)d_in[12];  // [D,V]
    const float* bout   = (const float*)d_in[13];

    float* out    = (float*)d_out;
    float* selfA  = out + 65536000L;
    float* crossA = selfA + 67108864L;

    // workspace carve
    char* p = (char*)d_ws;
    auto carve = [&](size_t bytes) { char* r = p; p += (bytes + 255) & ~255UL; return r; };
    float* x      = (float*)carve(1048576L * 4);
    short* xh     = (short*)carve(1048576L * 2);
    short* ench   = (short*)carve(1048576L * 2);
    short* qh     = (short*)carve(2097152L * 2);   // head-major Q|K hi
    short* ql     = (short*)carve(2097152L * 2);   // head-major Q|K lo
    short* vth    = (short*)carve(1048576L * 2);   // transposed V hi
    short* vtl    = (short*)carve(1048576L * 2);
    short* oh     = (short*)carve(1048576L * 2);
    short* t1h    = (short*)carve(4194304L * 2);   // FFN1 out hi
    float* part   = (float*)carve(4L * PSLAB * 4); // 4 K-split slabs
    short* WTLh   = (short*)carve(4194304L * 2);   // per-layer weights T hi
    short* WTh    = (short*)carve(8192000L * 2);   // vocab chunk T hi

    const long PW = 262144L;    // 512*512
    const long HS = 1048576L;   // per attention operand slab

    embed_pe_kernel<<<4096, 256, 0, stream>>>(tokens, emb, x, xh);
    cvt_kernel<<<1024, 256, 0, stream>>>(enc, ench);

    for (int l = 0; l < NLAYER; ++l) {
        const float* bl = bqkvo + (long)l * 4096L;
        const float* bc = bl + 2048;
        const float* g  = lng + (long)l * 3 * 512;
        const float* bb = lnb + (long)l * 3 * 512;

        wtrans_layer_kernel<<<1024, 256, 0, stream>>>(Wqkvo, W1, W2, l, WTLh);

        // ---- self-attention ----
        gemm_mfma_kernel<64,64,0,3,true><<<dim3(8, 32, 3), 256, 0, stream>>>(
            xh, WTLh, bl, nullptr, qh, ql, vth, vtl,
            512, 512, 512, 0, PW, 512, HS, 0, /*scaledZ=*/0, /*vtZ=*/2);
        attn_fused_kernel<true><<<dim3(32, 16), 128, 0, stream>>>(
            qh, ql, qh + HS, ql + HS, vth, vtl,
            selfA + (long)l * 16777216L, oh);
        gemm_mfma_kernel<64,64,0,5,true><<<dim3(8, 32, 2), 256, 0, stream>>>(
            oh, WTLh + 3*PW, nullptr, part, nullptr, nullptr,
            nullptr, nullptr, 256, 512, 512, 512, 0, 0, PSLAB, 256, -1, -1);
        add_ln_kernel<2><<<MROWS, 256, 0, stream>>>(
            x, part, PSLAB, bl + 3*512, g, bb, x, xh);

        // ---- cross-attention ----
        gemm_mfma_kernel<64,64,0,5,true><<<dim3(8, 32, 2), 256, 0, stream>>>(
            xh, WTLh + 4*PW, nullptr, part, nullptr, nullptr,
            nullptr, nullptr, 256, 512, 512, 512, 0, 0, PSLAB, 256, -1, -1);
        qc_combine_kernel<<<1024, 256, 0, stream>>>(part, part + PSLAB, bc, qh, ql);
        gemm_mfma_kernel<64,64,0,3,true><<<dim3(8, 32, 2), 256, 0, stream>>>(
            ench, WTLh + 5*PW, bc + 512, nullptr,
            qh + HS, ql + HS, vth, vtl,
            512, 512, 512, 0, PW, 512, HS, 0, /*scaledZ=*/-1, /*vtZ=*/1);
        attn_fused_kernel<false><<<dim3(32, 16), 128, 0, stream>>>(
            qh, ql, qh + HS, ql + HS, vth, vtl,
            crossA + (long)l * 16777216L, oh);
        gemm_mfma_kernel<64,64,0,5,true><<<dim3(8, 32, 2), 256, 0, stream>>>(
            oh, WTLh + 7*PW, nullptr, part, nullptr, nullptr,
            nullptr, nullptr, 256, 512, 512, 512, 0, 0, PSLAB, 256, -1, -1);
        add_ln_kernel<2><<<MROWS, 256, 0, stream>>>(
            x, part, PSLAB, bc + 3*512, g + 512, bb + 512, x, xh);

        // ---- FFN ----
        gemm_mfma_kernel<64,64,1,2,true><<<dim3(32, 32, 1), 256, 0, stream>>>(
            xh, WTLh + 2097152L, b1 + (long)l * 2048,
            nullptr, t1h, nullptr, nullptr, nullptr,
            512, 512, 512, 2048, 0, 0, 0, 0, -1, -1);
        gemm_mfma_kernel<64,64,0,5,true><<<dim3(8, 32, 4), 256, 0, stream>>>(
            t1h, WTLh + 3145728L, nullptr, part,
            nullptr, nullptr, nullptr, nullptr,
            512, 2048, 2048, 512, 0, 0, PSLAB, 512, -1, -1);
        add_ln_kernel<4><<<MROWS, 256, 0, stream>>>(
            x, part, PSLAB, b2 + (long)l * 512, g + 1024, bb + 1024, x, xh);
    }

    // ---- final vocab projection, two 16000-wide chunks ----
    for (int c = 0; c < 2; ++c) {
        wtrans_kernel<<<dim3(250, 8, 1), 256, 0, stream>>>(
            Wout + c * 16000, WTh, 512, VOCAB);
        gemm_mfma_kernel<128,128,0,0,true><<<dim3(125, 16, 1), 256, 0, stream>>>(
            xh, WTh, bout + c * 16000, out + c * 16000,
            nullptr, nullptr, nullptr, nullptr,
            512, 512, 512, VOCAB, 0, 0, 0, 0, -1, -1);
    }
}

// Round 14
// 1033.441 us; speedup vs baseline: 1.4015x; 1.0359x over previous
//
#include <hip/hip_runtime.h>
#include <hip/hip_bf16.h>

// ---------------------------------------------------------------------------
// Transformer decoder, fp32 I/O. GEMMs: pure bf16 1-product. Attention:
// QK keeps 3-product hi/lo (probs are graded outputs); PV is 1-product
// (P_hi * V_hi) -> 53 KB LDS, 3 blocks/CU.
// B=2, ST=SS=1024, D=512, H=8, DK=64, L=4, DFF=2048, V=32000.
// ---------------------------------------------------------------------------

#define D_MODEL 512
#define NHEAD   8
#define DKH     64
#define SEQ     1024
#define NLAYER  4
#define DFF_    2048
#define VOCAB   32000
#define BATCH   2
#define MROWS   (BATCH*SEQ)   // 2048
#define PSLAB   1048576L

typedef short bf16x8 __attribute__((ext_vector_type(8)));
typedef short short4v __attribute__((ext_vector_type(4)));
typedef float f32x4  __attribute__((ext_vector_type(4)));

static __device__ __forceinline__ short f2bf(float f) {
    __hip_bfloat16 h = __float2bfloat16(f);
    return *reinterpret_cast<short*>(&h);
}
static __device__ __forceinline__ float bf2f(short s) {
    __hip_bfloat16 h = *reinterpret_cast<__hip_bfloat16*>(&s);
    return __bfloat162float(h);
}
static __device__ __forceinline__ void gld16(const void* g, void* l) {
    __builtin_amdgcn_global_load_lds(
        (__attribute__((address_space(1))) void*)(void*)g,
        (__attribute__((address_space(3))) void*)l, 16, 0, 0);
}

// ---------------- embedding + positional encoding + hi ----------------------
__global__ __launch_bounds__(256) void embed_pe_kernel(
    const int* __restrict__ tokens, const float* __restrict__ emb,
    float* __restrict__ x, short* __restrict__ xh)
{
    long idx = (long)blockIdx.x * 256 + threadIdx.x;   // over 1,048,576
    int  d   = (int)(idx & (D_MODEL - 1));
    long row = idx >> 9;
    int  s   = (int)(row & (SEQ - 1));
    int  tok = tokens[row];
    float twoi = (float)((d >> 1) << 1);
    float div  = expf(twoi * (-9.210340371976184f / 512.0f));
    float arg  = (float)s * div;
    float pe   = (d & 1) ? cosf(arg) : sinf(arg);
    float v = emb[(long)tok * D_MODEL + d] * 22.62741699796952f + pe; // sqrt(512)
    x[idx] = v;
    xh[idx] = f2bf(v);
}

// ---------------- fp32 -> bf16 hi -------------------------------------------
__global__ __launch_bounds__(256) void cvt_kernel(
    const float* __restrict__ in, short* __restrict__ h)
{
    long e = ((long)blockIdx.x * 256 + threadIdx.x) * 4;
    float4 v = *(const float4*)&in[e];
    short4v hv;
    hv[0] = f2bf(v.x); hv[1] = f2bf(v.y); hv[2] = f2bf(v.z); hv[3] = f2bf(v.w);
    *(short4v*)&h[e] = hv;
}

// ---------------- weight transpose-convert: W[K,N] -> WT[N,K] hi ------------
__global__ __launch_bounds__(256) void wtrans_kernel(
    const float* __restrict__ W, short* __restrict__ Th,
    int K, int ldW)
{
    const int n0 = blockIdx.x * 64, k0 = blockIdx.y * 64;
    __shared__ float tile[64][65];
    const int t = threadIdx.x;
#pragma unroll
    for (int i = 0; i < 4; ++i) {
        int e = t + i * 256; int kk = e >> 4; int nn = (e & 15) * 4;
        float4 v = *(const float4*)&W[(long)(k0 + kk) * ldW + n0 + nn];
        tile[kk][nn] = v.x; tile[kk][nn + 1] = v.y;
        tile[kk][nn + 2] = v.z; tile[kk][nn + 3] = v.w;
    }
    __syncthreads();
    const int n = t >> 2, ks = (t & 3) * 16;
    short h8[16];
#pragma unroll
    for (int j = 0; j < 16; ++j) h8[j] = f2bf(tile[ks + j][n]);
    long base = (long)(n0 + n) * K + k0 + ks;
    *(bf16x8*)&Th[base]     = *(bf16x8*)&h8[0];
    *(bf16x8*)&Th[base + 8] = *(bf16x8*)&h8[8];
}

// ---------------- merged per-layer weight transpose (10 matrices, hi only) --
__global__ __launch_bounds__(256) void wtrans_layer_kernel(
    const float* __restrict__ Wqkvo, const float* __restrict__ W1,
    const float* __restrict__ W2, int l,
    short* __restrict__ Th)
{
    const int j = blockIdx.x;
    const float* W; int ldW, K; long dstOff; int n0, k0;
    if (j < 512) {
        int mat = j >> 6, tile_ = j & 63;
        W = Wqkvo + (long)l * 2097152L + (long)mat * 262144L;
        ldW = 512; K = 512; dstOff = (long)mat * 262144L;
        n0 = (tile_ & 7) * 64; k0 = (tile_ >> 3) * 64;
    } else if (j < 768) {
        int t2 = j - 512;
        W = W1 + (long)l * 1048576L; ldW = 2048; K = 512; dstOff = 2097152L;
        n0 = (t2 & 31) * 64; k0 = (t2 >> 5) * 64;
    } else {
        int t3 = j - 768;
        W = W2 + (long)l * 1048576L; ldW = 512; K = 2048; dstOff = 3145728L;
        n0 = (t3 & 7) * 64; k0 = (t3 >> 3) * 64;
    }
    __shared__ float tile[64][65];
    const int t = threadIdx.x;
#pragma unroll
    for (int i = 0; i < 4; ++i) {
        int e = t + i * 256; int kk = e >> 4; int nn = (e & 15) * 4;
        float4 v = *(const float4*)&W[(long)(k0 + kk) * ldW + n0 + nn];
        tile[kk][nn] = v.x; tile[kk][nn + 1] = v.y;
        tile[kk][nn + 2] = v.z; tile[kk][nn + 3] = v.w;
    }
    __syncthreads();
    const int n = t >> 2, ks = (t & 3) * 16;
    short h8[16];
#pragma unroll
    for (int j2 = 0; j2 < 16; ++j2) h8[j2] = f2bf(tile[ks + j2][n]);
    long base = dstOff + (long)(n0 + n) * K + k0 + ks;
    *(bf16x8*)&Th[base]     = *(bf16x8*)&h8[0];
    *(bf16x8*)&Th[base + 8] = *(bf16x8*)&h8[8];
}

// ---------------- 1-product MFMA GEMM: C = act(Ah@Bh^T + bias) --------------
// K-window at z*kOff. MODE 0: fp32+bias. MODE 2: bf16 hi+bias(+relu).
// MODE 3: head-major attn operand w/ dk swizzle; z<vtZ -> Q/K hi/lo (scaled
// if z==scaledZ); z==vtZ -> transposed V, hi only. MODE 5: fp32 partial.
// DBUF: double-buffered LDS, STAGE(k+1) before compute(k), 1 barrier/K-step.
template<int BM, int BN, int ACT, int MODE, bool DBUF>
__global__ __launch_bounds__(256) void gemm_mfma_kernel(
    const short* __restrict__ Ah, const short* __restrict__ Bh,
    const float* __restrict__ bias, float* __restrict__ C,
    short* __restrict__ Ch, short* __restrict__ Cl,
    short* __restrict__ VTh,
    int Keff, int ldA, int ldB, int ldc,
    long zB, long zBias, long zC, int kOff, int scaledZ, int vtZ)
{
    constexpr int NB   = DBUF ? 2 : 1;
    constexpr int MT_M = BM / 32;
    constexpr int MT_N = BN / 32;
    const long z = blockIdx.z;
    Bh += z * zB;
    if (MODE != 5) bias += z * zBias;

    const int n0 = blockIdx.x * BN, m0 = blockIdx.y * BM;
    const int t = threadIdx.x;
    const int w = t >> 6, lane = t & 63;
    const int wm = w >> 1, wn = w & 1;
    const int lr = lane & 15, ks = lane >> 4;

    __shared__ short sAh[NB][BM * 32];
    __shared__ short sBh[NB][BN * 32];

    f32x4 acc[MT_M][MT_N];
#pragma unroll
    for (int i = 0; i < MT_M; ++i)
#pragma unroll
        for (int j = 0; j < MT_N; ++j) acc[i][j] = (f32x4){0.f, 0.f, 0.f, 0.f};

    const long rowA = ((long)m0 * ldA + (long)z * kOff) * 2;   // bytes
    const long rowB = ((long)n0 * ldB + (long)z * kOff) * 2;

    auto STAGE = [&](int buf, int k0) {
#pragma unroll
        for (int i = 0; i < BM / 64; ++i) {
            const int  L = i * 4096 + t * 16;
            const int  r = L >> 6, s = L & 63;
            const long gb = ((long)r * ldA + k0) * 2 + s;
            gld16((const char*)Ah + rowA + gb, (char*)&sAh[buf][0] + L);
        }
#pragma unroll
        for (int i = 0; i < BN / 64; ++i) {
            const int  L = i * 4096 + t * 16;
            const int  r = L >> 6, s = L & 63;
            const long gb = ((long)r * ldB + k0) * 2 + s;
            gld16((const char*)Bh + rowB + gb, (char*)&sBh[buf][0] + L);
        }
    };
    auto COMPUTE = [&](int buf) {
        bf16x8 ah[MT_M], bh[MT_N];
#pragma unroll
        for (int mt = 0; mt < MT_M; ++mt) {
            int row = wm * (BM / 2) + mt * 16 + lr;
            ah[mt] = *(const bf16x8*)&sAh[buf][row * 32 + ks * 8];
        }
#pragma unroll
        for (int nt = 0; nt < MT_N; ++nt) {
            int col = wn * (BN / 2) + nt * 16 + lr;
            bh[nt] = *(const bf16x8*)&sBh[buf][col * 32 + ks * 8];
        }
#pragma unroll
        for (int mt = 0; mt < MT_M; ++mt)
#pragma unroll
            for (int nt = 0; nt < MT_N; ++nt)
                acc[mt][nt] = __builtin_amdgcn_mfma_f32_16x16x32_bf16(
                    ah[mt], bh[nt], acc[mt][nt], 0, 0, 0);
    };

    if (DBUF) {
        STAGE(0, 0);
        __syncthreads();
        int cur = 0;
        for (int k0 = 0; k0 < Keff; k0 += 32) {
            if (k0 + 32 < Keff) STAGE(cur ^ 1, k0 + 32);
            COMPUTE(cur);
            __syncthreads();
            cur ^= 1;
        }
    } else {
        for (int k0 = 0; k0 < Keff; k0 += 32) {
            STAGE(0, k0);
            __syncthreads();
            COMPUTE(0);
            __syncthreads();
        }
    }

    const int rq = lane >> 4, cq = lane & 15;
#pragma unroll
    for (int mt = 0; mt < MT_M; ++mt)
#pragma unroll
        for (int nt = 0; nt < MT_N; ++nt) {
            int gr0 = m0 + wm * (BM / 2) + mt * 16 + rq * 4;
            int gc  = n0 + wn * (BN / 2) + nt * 16 + cq;
            float vv[4];
            float bv = (MODE == 5) ? 0.f : bias[gc];
#pragma unroll
            for (int i = 0; i < 4; ++i) {
                float v = acc[mt][nt][i] + bv;
                if (ACT == 1) v = fmaxf(v, 0.f);
                vv[i] = v;
            }
            if (MODE == 0 || MODE == 5) {
#pragma unroll
                for (int i = 0; i < 4; ++i)
                    C[(long)(gr0 + i) * ldc + gc + z * zC] = vv[i];
            } else if (MODE == 2) {
#pragma unroll
                for (int i = 0; i < 4; ++i)
                    Ch[(long)(gr0 + i) * ldc + gc] = f2bf(vv[i]);
            } else {               // MODE 3
                if ((int)z == vtZ) {
                    int b = gr0 >> 10, s0 = gr0 & (SEQ - 1);
                    int hh2 = gc >> 6, dk = gc & 63;
                    int swz = (((dk >> 1) & 3) << 3) | (((dk >> 3) & 1) << 5);
                    long base = (((long)(b * NHEAD + hh2)) * 64 + dk) * 1024
                              + (long)(((s0 & ~7) ^ swz) | (s0 & 7));
                    short4v hv;
#pragma unroll
                    for (int i = 0; i < 4; ++i) hv[i] = f2bf(vv[i]);
                    *(short4v*)&VTh[base] = hv;
                } else {
                    float sc = ((int)z == scaledZ) ? 0.125f : 1.f;
#pragma unroll
                    for (int i = 0; i < 4; ++i) {
                        float v2 = vv[i] * sc;
                        int gr = gr0 + i;
                        int b = gr >> 10, s = gr & (SEQ - 1);
                        int hh2 = gc >> 6, dk = gc & 63;
                        int dks = dk ^ (((s >> 1) & 7) << 3);
                        long oidx = z * zC +
                            (((long)(b * NHEAD + hh2)) * SEQ + s) * 64 + dks;
                        short h = f2bf(v2);
                        Ch[oidx] = h;
                        Cl[oidx] = f2bf(v2 - bf2f(h));
                    }
                }
            }
        }
}

// ---------------- Qc combine: part0+part1+bias -> *0.125 -> MODE3 layout ----
__global__ __launch_bounds__(256) void qc_combine_kernel(
    const float* __restrict__ p0, const float* __restrict__ p1,
    const float* __restrict__ bias, short* __restrict__ Qh, short* __restrict__ Ql)
{
    long idx = (long)blockIdx.x * 256 + threadIdx.x;   // 262144 total
    int gr = (int)(idx >> 7);
    int gc4 = (int)(idx & 127) * 4;
    float4 a = *(const float4*)&p0[(long)gr * 512 + gc4];
    float4 b2 = *(const float4*)&p1[(long)gr * 512 + gc4];
    float4 bv = *(const float4*)&bias[gc4];
    float v[4] = {(a.x + b2.x + bv.x) * 0.125f, (a.y + b2.y + bv.y) * 0.125f,
                  (a.z + b2.z + bv.z) * 0.125f, (a.w + b2.w + bv.w) * 0.125f};
    int b = gr >> 10, s = gr & (SEQ - 1);
    int hh = gc4 >> 6, dk4 = gc4 & 63;
    int dks = dk4 ^ (((s >> 1) & 7) << 3);
    long o = (((long)(b * NHEAD + hh)) * SEQ + s) * 64 + dks;
    short4v hv, lv;
#pragma unroll
    for (int i = 0; i < 4; ++i) {
        short h = f2bf(v[i]);
        hv[i] = h;
        lv[i] = f2bf(v[i] - bf2f(h));
    }
    *(short4v*)&Qh[o] = hv;
    *(short4v*)&Ql[o] = lv;
}

// ---------------- fused attention: 32 q-rows, 2 waves, 3 blocks/CU ----------
// QK: 3-product hi/lo (probs fidelity). PV: 1-product (P_hi * V_hi).
// LDS = 16+16+16+5 = 53 KB.
template<bool CAUSAL>
__global__ __launch_bounds__(128) void attn_fused_kernel(
    const short* __restrict__ Qh, const short* __restrict__ Ql,
    const short* __restrict__ Kh, const short* __restrict__ Kl,
    const short* __restrict__ VTh,
    float* __restrict__ attn, short* __restrict__ Oh)
{
    const int strip = blockIdx.x, bh = blockIdx.y;
    const int q0 = strip * 32;
    const int t = threadIdx.x, w = t >> 6, lane = t & 63;
    const int lr = lane & 15, ks = lane >> 4;
    const int rq = lane >> 4, cq = lane & 15;
    const int sxq = (lr >> 1) & 7;

    __shared__ short sKh[2][64*64], sKl[2][64*64];   // 32 KB
    __shared__ short sVh[2][64*64];                  // 16 KB
    __shared__ short sPh[2][16*80];                  //  5 KB

    const int diag  = strip >> 1;
    const int ktmax = CAUSAL ? diag + 1 : 16;

    // Q stage (32 rows hi+lo) via sKh[0]/sKl[0]
    {
        const long qb = ((long)bh * SEQ + q0) * 128;
#pragma unroll
        for (int i2 = 0; i2 < 2; ++i2) {
            int L = i2 * 2048 + t * 16; int r = L >> 7, off = L & 127;
            gld16((const char*)Qh + qb + (long)r*128 + off, (char*)&sKh[0][0] + L);
            gld16((const char*)Ql + qb + (long)r*128 + off, (char*)&sKl[0][0] + L);
        }
    }
    __syncthreads();
    bf16x8 qa[2][2];
#pragma unroll
    for (int k0 = 0; k0 < 2; ++k0) {
        int o = (w*16 + lr) * 64 + ((k0*32 + ks*8) ^ (sxq << 3));
        qa[k0][0] = *(const bf16x8*)&sKh[0][o];
        qa[k0][1] = *(const bf16x8*)&sKl[0][o];
    }
    __syncthreads();

    auto stageK = [&](int buf, int kt) {
        const long kb = ((long)bh * SEQ + kt*64) * 128;
#pragma unroll
        for (int i2 = 0; i2 < 4; ++i2) {
            int L = i2*2048 + t*16; int r = L >> 7, off = L & 127;
            gld16((const char*)Kh + kb + (long)r*128 + off, (char*)&sKh[buf][0] + L);
            gld16((const char*)Kl + kb + (long)r*128 + off, (char*)&sKl[buf][0] + L);
        }
    };
    auto stageV = [&](int buf, int kt) {
        const long vb = ((long)bh * 64) * 2048 + (long)kt * 128;
#pragma unroll
        for (int i2 = 0; i2 < 4; ++i2) {
            int L = i2*2048 + t*16; int r = L >> 7, off = L & 127;
            gld16((const char*)VTh + vb + (long)r*2048 + off, (char*)&sVh[buf][0] + L);
        }
    };
    auto scoresOf = [&](int buf, int kt, f32x4* sc) {
#pragma unroll
        for (int nt = 0; nt < 4; ++nt) sc[nt] = (f32x4){0.f, 0.f, 0.f, 0.f};
#pragma unroll
        for (int k0 = 0; k0 < 2; ++k0) {
            bf16x8 kh[4], kl[4];
#pragma unroll
            for (int nt = 0; nt < 4; ++nt) {
                int o = (nt*16 + lr) * 64 + ((k0*32 + ks*8) ^ (sxq << 3));
                kh[nt] = *(const bf16x8*)&sKh[buf][o];
                kl[nt] = *(const bf16x8*)&sKl[buf][o];
            }
#pragma unroll
            for (int nt = 0; nt < 4; ++nt) {
                sc[nt] = __builtin_amdgcn_mfma_f32_16x16x32_bf16(
                    qa[k0][0], kh[nt], sc[nt], 0, 0, 0);
                sc[nt] = __builtin_amdgcn_mfma_f32_16x16x32_bf16(
                    qa[k0][0], kl[nt], sc[nt], 0, 0, 0);
                sc[nt] = __builtin_amdgcn_mfma_f32_16x16x32_bf16(
                    qa[k0][1], kh[nt], sc[nt], 0, 0, 0);
            }
        }
        if (CAUSAL && kt == diag) {
            int row = q0 + w*16 + rq*4;
#pragma unroll
            for (int nt = 0; nt < 4; ++nt) {
                int col = kt*64 + nt*16 + cq;
#pragma unroll
                for (int i = 0; i < 4; ++i)
                    if (col > row + i) sc[nt][i] = -1e9f;
            }
        }
    };

    // ---- pass 1: online max + sum ----
    float m[4]   = {-3e38f, -3e38f, -3e38f, -3e38f};
    float sum[4] = {0.f, 0.f, 0.f, 0.f};
    int cur = 0;
    stageK(0, 0);
    __syncthreads();
    for (int kt = 0; kt < ktmax; ++kt) {
        if (kt + 1 < ktmax) stageK(cur ^ 1, kt + 1);
        f32x4 sc[4];
        scoresOf(cur, kt, sc);
#pragma unroll
        for (int i = 0; i < 4; ++i) {
            float tm = fmaxf(fmaxf(sc[0][i], sc[1][i]), fmaxf(sc[2][i], sc[3][i]));
#pragma unroll
            for (int d2 = 1; d2 <= 8; d2 <<= 1) tm = fmaxf(tm, __shfl_xor(tm, d2, 64));
            float mn = fmaxf(m[i], tm);
            float ps = __expf(sc[0][i] - mn) + __expf(sc[1][i] - mn)
                     + __expf(sc[2][i] - mn) + __expf(sc[3][i] - mn);
#pragma unroll
            for (int d2 = 1; d2 <= 8; d2 <<= 1) ps += __shfl_xor(ps, d2, 64);
            sum[i] = sum[i] * __expf(m[i] - mn) + ps;
            m[i] = mn;
        }
        __syncthreads();
        cur ^= 1;
    }
    float inv[4];
#pragma unroll
    for (int i = 0; i < 4; ++i) inv[i] = 1.f / sum[i];

    // ---- pass 2: recompute, probs out, PV (1-product) ----
    f32x4 acco[4];
#pragma unroll
    for (int nt = 0; nt < 4; ++nt) acco[nt] = (f32x4){0.f, 0.f, 0.f, 0.f};

    cur = 0;
    stageK(0, 0); stageV(0, 0);
    __syncthreads();
    for (int kt = 0; kt < 16; ++kt) {
        if (kt >= ktmax) {
#pragma unroll
            for (int nt = 0; nt < 4; ++nt)
#pragma unroll
                for (int i = 0; i < 4; ++i)
                    attn[((long)bh << 20) + ((long)(q0 + w*16 + rq*4 + i) << 10)
                         + kt*64 + nt*16 + cq] = 0.f;
            continue;
        }
        if (kt + 1 < ktmax) { stageK(cur ^ 1, kt + 1); stageV(cur ^ 1, kt + 1); }
        f32x4 sc[4];
        scoresOf(cur, kt, sc);
#pragma unroll
        for (int nt = 0; nt < 4; ++nt)
#pragma unroll
            for (int i = 0; i < 4; ++i) {
                float p = __expf(sc[nt][i] - m[i]) * inv[i];
                attn[((long)bh << 20) + ((long)(q0 + w*16 + rq*4 + i) << 10)
                     + kt*64 + nt*16 + cq] = p;
                sPh[w][(rq*4 + i)*80 + nt*16 + cq] = f2bf(p);
            }
#pragma unroll
        for (int k0 = 0; k0 < 2; ++k0) {
            bf16x8 pah = *(const bf16x8*)&sPh[w][lr*80 + k0*32 + ks*8];
#pragma unroll
            for (int nt = 0; nt < 4; ++nt) {
                int dk = nt*16 + lr;
                int swz = (((dk >> 1) & 3) << 3) | (((dk >> 3) & 1) << 5);
                int koff = (k0*32 + ks*8) ^ swz;
                bf16x8 vh8 = *(const bf16x8*)&sVh[cur][dk*64 + koff];
                acco[nt] = __builtin_amdgcn_mfma_f32_16x16x32_bf16(
                    pah, vh8, acco[nt], 0, 0, 0);
            }
        }
        __syncthreads();
        cur ^= 1;
    }

    const int b = bh >> 3, hh_ = bh & 7;
#pragma unroll
    for (int nt = 0; nt < 4; ++nt)
#pragma unroll
        for (int i = 0; i < 4; ++i) {
            long oidx = ((long)(b * SEQ + q0 + w*16 + rq*4 + i)) * D_MODEL
                      + hh_*64 + nt*16 + cq;
            Oh[oidx] = f2bf(acco[nt][i]);
        }
}

// ---------------- residual + NS partial slabs + bias + LayerNorm + hi -------
template<int NS>
__global__ __launch_bounds__(256) void add_ln_kernel(
    const float* __restrict__ xin, const float* __restrict__ part, long PS,
    const float* __restrict__ bias,
    const float* __restrict__ g, const float* __restrict__ bb,
    float* __restrict__ xout, short* __restrict__ xh)
{
    long row = blockIdx.x;
    const float* xr = xin + row * D_MODEL;
    float*       xo = xout+ row * D_MODEL;
    short*       hh = xh  + row * D_MODEL;
    int t = threadIdx.x;

    float a0 = xr[t]       + bias[t];
    float a1 = xr[t + 256] + bias[t + 256];
#pragma unroll
    for (int s2 = 0; s2 < NS; ++s2) {
        a0 += part[s2 * PS + row * D_MODEL + t];
        a1 += part[s2 * PS + row * D_MODEL + t + 256];
    }

    float s = a0 + a1;
#pragma unroll
    for (int m = 32; m; m >>= 1) s += __shfl_xor(s, m, 64);
    __shared__ float red1[4];
    __shared__ float red2[4];
    int w = t >> 6, lane = t & 63;
    if (lane == 0) red1[w] = s;
    __syncthreads();
    float mean = (red1[0] + red1[1] + red1[2] + red1[3]) * (1.f / 512.f);

    float d0 = a0 - mean, d1 = a1 - mean;
    float q = d0 * d0 + d1 * d1;
#pragma unroll
    for (int m = 32; m; m >>= 1) q += __shfl_xor(q, m, 64);
    if (lane == 0) red2[w] = q;
    __syncthreads();
    float var  = (red2[0] + red2[1] + red2[2] + red2[3]) * (1.f / 512.f);
    float rstd = rsqrtf(var + 1e-5f);

    float r0 = d0 * rstd * g[t]       + bb[t];
    float r1 = d1 * rstd * g[t + 256] + bb[t + 256];
    xo[t] = r0; xo[t + 256] = r1;
    hh[t] = f2bf(r0);
    hh[t + 256] = f2bf(r1);
}

// ---------------------------------------------------------------------------
extern "C" void kernel_launch(void* const* d_in, const int* in_sizes, int n_in,
                              void* d_out, int out_size, void* d_ws, size_t ws_size,
                              hipStream_t stream)
{
    const int*   tokens = (const int*)  d_in[0];
    const float* enc    = (const float*)d_in[1];
    const float* emb    = (const float*)d_in[3];
    const float* Wqkvo  = (const float*)d_in[4];   // [L,2,4,D,D]
    const float* bqkvo  = (const float*)d_in[5];   // [L,2,4,D]
    const float* W1     = (const float*)d_in[6];   // [L,D,DFF]
    const float* b1     = (const float*)d_in[7];
    const float* W2     = (const float*)d_in[8];   // [L,DFF,D]
    const float* b2     = (const float*)d_in[9];
    const float* lng    = (const float*)d_in[10];  // [L,3,D]
    const float* lnb    = (const float*)d_in[11];
    const float* Wout   = (const float*)d_in[12];  // [D,V]
    const float* bout   = (const float*)d_in[13];

    float* out    = (float*)d_out;
    float* selfA  = out + 65536000L;
    float* crossA = selfA + 67108864L;

    // workspace carve
    char* p = (char*)d_ws;
    auto carve = [&](size_t bytes) { char* r = p; p += (bytes + 255) & ~255UL; return r; };
    float* x      = (float*)carve(1048576L * 4);
    short* xh     = (short*)carve(1048576L * 2);
    short* ench   = (short*)carve(1048576L * 2);
    short* qh     = (short*)carve(2097152L * 2);   // head-major Q|K hi
    short* ql     = (short*)carve(2097152L * 2);   // head-major Q|K lo
    short* vth    = (short*)carve(1048576L * 2);   // transposed V hi
    short* oh     = (short*)carve(1048576L * 2);
    short* t1h    = (short*)carve(4194304L * 2);   // FFN1 out hi
    float* part   = (float*)carve(4L * PSLAB * 4); // 4 K-split slabs
    short* WTLh   = (short*)carve(4194304L * 2);   // per-layer weights T hi
    short* WTh    = (short*)carve(8192000L * 2);   // vocab chunk T hi

    const long PW = 262144L;    // 512*512
    const long HS = 1048576L;   // per attention operand slab

    embed_pe_kernel<<<4096, 256, 0, stream>>>(tokens, emb, x, xh);
    cvt_kernel<<<1024, 256, 0, stream>>>(enc, ench);

    for (int l = 0; l < NLAYER; ++l) {
        const float* bl = bqkvo + (long)l * 4096L;
        const float* bc = bl + 2048;
        const float* g  = lng + (long)l * 3 * 512;
        const float* bb = lnb + (long)l * 3 * 512;

        wtrans_layer_kernel<<<1024, 256, 0, stream>>>(Wqkvo, W1, W2, l, WTLh);

        // ---- self-attention ----
        gemm_mfma_kernel<64,64,0,3,true><<<dim3(8, 32, 3), 256, 0, stream>>>(
            xh, WTLh, bl, nullptr, qh, ql, vth,
            512, 512, 512, 0, PW, 512, HS, 0, /*scaledZ=*/0, /*vtZ=*/2);
        attn_fused_kernel<true><<<dim3(32, 16), 128, 0, stream>>>(
            qh, ql, qh + HS, ql + HS, vth,
            selfA + (long)l * 16777216L, oh);
        gemm_mfma_kernel<64,64,0,5,true><<<dim3(8, 32, 2), 256, 0, stream>>>(
            oh, WTLh + 3*PW, nullptr, part, nullptr, nullptr, nullptr,
            256, 512, 512, 512, 0, 0, PSLAB, 256, -1, -1);
        add_ln_kernel<2><<<MROWS, 256, 0, stream>>>(
            x, part, PSLAB, bl + 3*512, g, bb, x, xh);

        // ---- cross-attention ----
        gemm_mfma_kernel<64,64,0,5,true><<<dim3(8, 32, 2), 256, 0, stream>>>(
            xh, WTLh + 4*PW, nullptr, part, nullptr, nullptr, nullptr,
            256, 512, 512, 512, 0, 0, PSLAB, 256, -1, -1);
        qc_combine_kernel<<<1024, 256, 0, stream>>>(part, part + PSLAB, bc, qh, ql);
        gemm_mfma_kernel<64,64,0,3,true><<<dim3(8, 32, 2), 256, 0, stream>>>(
            ench, WTLh + 5*PW, bc + 512, nullptr,
            qh + HS, ql + HS, vth,
            512, 512, 512, 0, PW, 512, HS, 0, /*scaledZ=*/-1, /*vtZ=*/1);
        attn_fused_kernel<false><<<dim3(32, 16), 128, 0, stream>>>(
            qh, ql, qh + HS, ql + HS, vth,
            crossA + (long)l * 16777216L, oh);
        gemm_mfma_kernel<64,64,0,5,true><<<dim3(8, 32, 2), 256, 0, stream>>>(
            oh, WTLh + 7*PW, nullptr, part, nullptr, nullptr, nullptr,
            256, 512, 512, 512, 0, 0, PSLAB, 256, -1, -1);
        add_ln_kernel<2><<<MROWS, 256, 0, stream>>>(
            x, part, PSLAB, bc + 3*512, g + 512, bb + 512, x, xh);

        // ---- FFN ----
        gemm_mfma_kernel<64,64,1,2,true><<<dim3(32, 32, 1), 256, 0, stream>>>(
            xh, WTLh + 2097152L, b1 + (long)l * 2048,
            nullptr, t1h, nullptr, nullptr,
            512, 512, 512, 2048, 0, 0, 0, 0, -1, -1);
        gemm_mfma_kernel<64,64,0,5,true><<<dim3(8, 32, 4), 256, 0, stream>>>(
            t1h, WTLh + 3145728L, nullptr, part,
            nullptr, nullptr, nullptr,
            512, 2048, 2048, 512, 0, 0, PSLAB, 512, -1, -1);
        add_ln_kernel<4><<<MROWS, 256, 0, stream>>>(
            x, part, PSLAB, b2 + (long)l * 512, g + 1024, bb + 1024, x, xh);
    }

    // ---- final vocab projection, two 16000-wide chunks ----
    for (int c = 0; c < 2; ++c) {
        wtrans_kernel<<<dim3(250, 8, 1), 256, 0, stream>>>(
            Wout + c * 16000, WTh, 512, VOCAB);
        gemm_mfma_kernel<128,128,0,0,true><<<dim3(125, 16, 1), 256, 0, stream>>>(
            xh, WTh, bout + c * 16000, out + c * 16000,
            nullptr, nullptr, nullptr,
            512, 512, 512, VOCAB, 0, 0, 0, 0, -1, -1);
    }
}

// Round 15
// 998.605 us; speedup vs baseline: 1.4504x; 1.0349x over previous
//
#include <hip/hip_runtime.h>
#include <hip/hip_bf16.h>

// ---------------------------------------------------------------------------
// Transformer decoder, fp32 I/O. GEMMs: pure bf16 1-product. Attention:
// QK 3-product hi/lo (prob fidelity), PV 1-product. Cross QKV merged into one
// z=3 MODE-3 GEMM via A-select (z>=aSwitchZ -> enc). No qc_combine.
// B=2, ST=SS=1024, D=512, H=8, DK=64, L=4, DFF=2048, V=32000.
// ---------------------------------------------------------------------------

#define D_MODEL 512
#define NHEAD   8
#define DKH     64
#define SEQ     1024
#define NLAYER  4
#define DFF_    2048
#define VOCAB   32000
#define BATCH   2
#define MROWS   (BATCH*SEQ)   // 2048
#define PSLAB   1048576L

typedef short bf16x8 __attribute__((ext_vector_type(8)));
typedef short short4v __attribute__((ext_vector_type(4)));
typedef float f32x4  __attribute__((ext_vector_type(4)));

static __device__ __forceinline__ short f2bf(float f) {
    __hip_bfloat16 h = __float2bfloat16(f);
    return *reinterpret_cast<short*>(&h);
}
static __device__ __forceinline__ float bf2f(short s) {
    __hip_bfloat16 h = *reinterpret_cast<__hip_bfloat16*>(&s);
    return __bfloat162float(h);
}
static __device__ __forceinline__ void gld16(const void* g, void* l) {
    __builtin_amdgcn_global_load_lds(
        (__attribute__((address_space(1))) void*)(void*)g,
        (__attribute__((address_space(3))) void*)l, 16, 0, 0);
}

// ---------------- embedding + positional encoding + hi ----------------------
__global__ __launch_bounds__(256) void embed_pe_kernel(
    const int* __restrict__ tokens, const float* __restrict__ emb,
    float* __restrict__ x, short* __restrict__ xh)
{
    long idx = (long)blockIdx.x * 256 + threadIdx.x;   // over 1,048,576
    int  d   = (int)(idx & (D_MODEL - 1));
    long row = idx >> 9;
    int  s   = (int)(row & (SEQ - 1));
    int  tok = tokens[row];
    float twoi = (float)((d >> 1) << 1);
    float div  = expf(twoi * (-9.210340371976184f / 512.0f));
    float arg  = (float)s * div;
    float pe   = (d & 1) ? cosf(arg) : sinf(arg);
    float v = emb[(long)tok * D_MODEL + d] * 22.62741699796952f + pe; // sqrt(512)
    x[idx] = v;
    xh[idx] = f2bf(v);
}

// ---------------- fp32 -> bf16 hi -------------------------------------------
__global__ __launch_bounds__(256) void cvt_kernel(
    const float* __restrict__ in, short* __restrict__ h)
{
    long e = ((long)blockIdx.x * 256 + threadIdx.x) * 4;
    float4 v = *(const float4*)&in[e];
    short4v hv;
    hv[0] = f2bf(v.x); hv[1] = f2bf(v.y); hv[2] = f2bf(v.z); hv[3] = f2bf(v.w);
    *(short4v*)&h[e] = hv;
}

// ---------------- weight transpose-convert: W[K,N] -> WT[N,K] hi ------------
__global__ __launch_bounds__(256) void wtrans_kernel(
    const float* __restrict__ W, short* __restrict__ Th,
    int K, int ldW)
{
    const int n0 = blockIdx.x * 64, k0 = blockIdx.y * 64;
    __shared__ float tile[64][65];
    const int t = threadIdx.x;
#pragma unroll
    for (int i = 0; i < 4; ++i) {
        int e = t + i * 256; int kk = e >> 4; int nn = (e & 15) * 4;
        float4 v = *(const float4*)&W[(long)(k0 + kk) * ldW + n0 + nn];
        tile[kk][nn] = v.x; tile[kk][nn + 1] = v.y;
        tile[kk][nn + 2] = v.z; tile[kk][nn + 3] = v.w;
    }
    __syncthreads();
    const int n = t >> 2, ks = (t & 3) * 16;
    short h8[16];
#pragma unroll
    for (int j = 0; j < 16; ++j) h8[j] = f2bf(tile[ks + j][n]);
    long base = (long)(n0 + n) * K + k0 + ks;
    *(bf16x8*)&Th[base]     = *(bf16x8*)&h8[0];
    *(bf16x8*)&Th[base + 8] = *(bf16x8*)&h8[8];
}

// ---------------- merged per-layer weight transpose (10 matrices, hi only) --
__global__ __launch_bounds__(256) void wtrans_layer_kernel(
    const float* __restrict__ Wqkvo, const float* __restrict__ W1,
    const float* __restrict__ W2, int l,
    short* __restrict__ Th)
{
    const int j = blockIdx.x;
    const float* W; int ldW, K; long dstOff; int n0, k0;
    if (j < 512) {
        int mat = j >> 6, tile_ = j & 63;
        W = Wqkvo + (long)l * 2097152L + (long)mat * 262144L;
        ldW = 512; K = 512; dstOff = (long)mat * 262144L;
        n0 = (tile_ & 7) * 64; k0 = (tile_ >> 3) * 64;
    } else if (j < 768) {
        int t2 = j - 512;
        W = W1 + (long)l * 1048576L; ldW = 2048; K = 512; dstOff = 2097152L;
        n0 = (t2 & 31) * 64; k0 = (t2 >> 5) * 64;
    } else {
        int t3 = j - 768;
        W = W2 + (long)l * 1048576L; ldW = 512; K = 2048; dstOff = 3145728L;
        n0 = (t3 & 7) * 64; k0 = (t3 >> 3) * 64;
    }
    __shared__ float tile[64][65];
    const int t = threadIdx.x;
#pragma unroll
    for (int i = 0; i < 4; ++i) {
        int e = t + i * 256; int kk = e >> 4; int nn = (e & 15) * 4;
        float4 v = *(const float4*)&W[(long)(k0 + kk) * ldW + n0 + nn];
        tile[kk][nn] = v.x; tile[kk][nn + 1] = v.y;
        tile[kk][nn + 2] = v.z; tile[kk][nn + 3] = v.w;
    }
    __syncthreads();
    const int n = t >> 2, ks = (t & 3) * 16;
    short h8[16];
#pragma unroll
    for (int j2 = 0; j2 < 16; ++j2) h8[j2] = f2bf(tile[ks + j2][n]);
    long base = dstOff + (long)(n0 + n) * K + k0 + ks;
    *(bf16x8*)&Th[base]     = *(bf16x8*)&h8[0];
    *(bf16x8*)&Th[base + 8] = *(bf16x8*)&h8[8];
}

// ---------------- 1-product MFMA GEMM: C = act(A@Bh^T + bias) ---------------
// A = (MODE==3 && z>=aSwitchZ) ? A2h : Ah.  K-window at z*kOff.
// MODE 0: fp32+bias. MODE 2: bf16 hi+bias(+relu). MODE 3: head-major attn
// operand w/ dk swizzle; z<vtZ non-V -> Q/K hi/lo (z==scaledZ -> *0.125);
// z==vtZ -> transposed V hi. MODE 5: fp32 partial, no bias.
// DBUF: double-buffered LDS, STAGE(k+1) before compute(k), 1 barrier/K-step.
template<int BM, int BN, int ACT, int MODE, bool DBUF>
__global__ __launch_bounds__(256) void gemm_mfma_kernel(
    const short* __restrict__ Ah, const short* __restrict__ A2h,
    const short* __restrict__ Bh,
    const float* __restrict__ bias, float* __restrict__ C,
    short* __restrict__ Ch, short* __restrict__ Cl,
    short* __restrict__ VTh,
    int Keff, int ldA, int ldB, int ldc,
    long zB, long zBias, long zC, int kOff, int scaledZ, int vtZ, int aSwitchZ)
{
    constexpr int NB   = DBUF ? 2 : 1;
    constexpr int MT_M = BM / 32;
    constexpr int MT_N = BN / 32;
    const long z = blockIdx.z;
    Bh += z * zB;
    if (MODE != 5) bias += z * zBias;

    const short* Au = (MODE == 3 && (int)z >= aSwitchZ) ? A2h : Ah;

    const int n0 = blockIdx.x * BN, m0 = blockIdx.y * BM;
    const int t = threadIdx.x;
    const int w = t >> 6, lane = t & 63;
    const int wm = w >> 1, wn = w & 1;
    const int lr = lane & 15, ks = lane >> 4;

    __shared__ short sAh[NB][BM * 32];
    __shared__ short sBh[NB][BN * 32];

    f32x4 acc[MT_M][MT_N];
#pragma unroll
    for (int i = 0; i < MT_M; ++i)
#pragma unroll
        for (int j = 0; j < MT_N; ++j) acc[i][j] = (f32x4){0.f, 0.f, 0.f, 0.f};

    const long rowA = ((long)m0 * ldA + (long)z * kOff) * 2;   // bytes
    const long rowB = ((long)n0 * ldB + (long)z * kOff) * 2;

    auto STAGE = [&](int buf, int k0) {
#pragma unroll
        for (int i = 0; i < BM / 64; ++i) {
            const int  L = i * 4096 + t * 16;
            const int  r = L >> 6, s = L & 63;
            const long gb = ((long)r * ldA + k0) * 2 + s;
            gld16((const char*)Au + rowA + gb, (char*)&sAh[buf][0] + L);
        }
#pragma unroll
        for (int i = 0; i < BN / 64; ++i) {
            const int  L = i * 4096 + t * 16;
            const int  r = L >> 6, s = L & 63;
            const long gb = ((long)r * ldB + k0) * 2 + s;
            gld16((const char*)Bh + rowB + gb, (char*)&sBh[buf][0] + L);
        }
    };
    auto COMPUTE = [&](int buf) {
        bf16x8 ah[MT_M], bh[MT_N];
#pragma unroll
        for (int mt = 0; mt < MT_M; ++mt) {
            int row = wm * (BM / 2) + mt * 16 + lr;
            ah[mt] = *(const bf16x8*)&sAh[buf][row * 32 + ks * 8];
        }
#pragma unroll
        for (int nt = 0; nt < MT_N; ++nt) {
            int col = wn * (BN / 2) + nt * 16 + lr;
            bh[nt] = *(const bf16x8*)&sBh[buf][col * 32 + ks * 8];
        }
#pragma unroll
        for (int mt = 0; mt < MT_M; ++mt)
#pragma unroll
            for (int nt = 0; nt < MT_N; ++nt)
                acc[mt][nt] = __builtin_amdgcn_mfma_f32_16x16x32_bf16(
                    ah[mt], bh[nt], acc[mt][nt], 0, 0, 0);
    };

    if (DBUF) {
        STAGE(0, 0);
        __syncthreads();
        int cur = 0;
        for (int k0 = 0; k0 < Keff; k0 += 32) {
            if (k0 + 32 < Keff) STAGE(cur ^ 1, k0 + 32);
            COMPUTE(cur);
            __syncthreads();
            cur ^= 1;
        }
    } else {
        for (int k0 = 0; k0 < Keff; k0 += 32) {
            STAGE(0, k0);
            __syncthreads();
            COMPUTE(0);
            __syncthreads();
        }
    }

    const int rq = lane >> 4, cq = lane & 15;
#pragma unroll
    for (int mt = 0; mt < MT_M; ++mt)
#pragma unroll
        for (int nt = 0; nt < MT_N; ++nt) {
            int gr0 = m0 + wm * (BM / 2) + mt * 16 + rq * 4;
            int gc  = n0 + wn * (BN / 2) + nt * 16 + cq;
            float vv[4];
            float bv = (MODE == 5) ? 0.f : bias[gc];
#pragma unroll
            for (int i = 0; i < 4; ++i) {
                float v = acc[mt][nt][i] + bv;
                if (ACT == 1) v = fmaxf(v, 0.f);
                vv[i] = v;
            }
            if (MODE == 0 || MODE == 5) {
#pragma unroll
                for (int i = 0; i < 4; ++i)
                    C[(long)(gr0 + i) * ldc + gc + z * zC] = vv[i];
            } else if (MODE == 2) {
#pragma unroll
                for (int i = 0; i < 4; ++i)
                    Ch[(long)(gr0 + i) * ldc + gc] = f2bf(vv[i]);
            } else {               // MODE 3
                if ((int)z == vtZ) {
                    int b = gr0 >> 10, s0 = gr0 & (SEQ - 1);
                    int hh2 = gc >> 6, dk = gc & 63;
                    int swz = (((dk >> 1) & 3) << 3) | (((dk >> 3) & 1) << 5);
                    long base = (((long)(b * NHEAD + hh2)) * 64 + dk) * 1024
                              + (long)(((s0 & ~7) ^ swz) | (s0 & 7));
                    short4v hv;
#pragma unroll
                    for (int i = 0; i < 4; ++i) hv[i] = f2bf(vv[i]);
                    *(short4v*)&VTh[base] = hv;
                } else {
                    float sc = ((int)z == scaledZ) ? 0.125f : 1.f;
#pragma unroll
                    for (int i = 0; i < 4; ++i) {
                        float v2 = vv[i] * sc;
                        int gr = gr0 + i;
                        int b = gr >> 10, s = gr & (SEQ - 1);
                        int hh2 = gc >> 6, dk = gc & 63;
                        int dks = dk ^ (((s >> 1) & 7) << 3);
                        long oidx = z * zC +
                            (((long)(b * NHEAD + hh2)) * SEQ + s) * 64 + dks;
                        short h = f2bf(v2);
                        Ch[oidx] = h;
                        Cl[oidx] = f2bf(v2 - bf2f(h));
                    }
                }
            }
        }
}

// ---------------- fused attention: 32 q-rows, 2 waves ------------------------
// QK: 3-product hi/lo (probs fidelity). PV: 1-product (P_hi * V_hi).
template<bool CAUSAL>
__global__ __launch_bounds__(128) void attn_fused_kernel(
    const short* __restrict__ Qh, const short* __restrict__ Ql,
    const short* __restrict__ Kh, const short* __restrict__ Kl,
    const short* __restrict__ VTh,
    float* __restrict__ attn, short* __restrict__ Oh)
{
    const int strip = blockIdx.x, bh = blockIdx.y;
    const int q0 = strip * 32;
    const int t = threadIdx.x, w = t >> 6, lane = t & 63;
    const int lr = lane & 15, ks = lane >> 4;
    const int rq = lane >> 4, cq = lane & 15;
    const int sxq = (lr >> 1) & 7;

    __shared__ short sKh[2][64*64], sKl[2][64*64];   // 32 KB
    __shared__ short sVh[2][64*64];                  // 16 KB
    __shared__ short sPh[2][16*80];                  //  5 KB

    const int diag  = strip >> 1;
    const int ktmax = CAUSAL ? diag + 1 : 16;

    {
        const long qb = ((long)bh * SEQ + q0) * 128;
#pragma unroll
        for (int i2 = 0; i2 < 2; ++i2) {
            int L = i2 * 2048 + t * 16; int r = L >> 7, off = L & 127;
            gld16((const char*)Qh + qb + (long)r*128 + off, (char*)&sKh[0][0] + L);
            gld16((const char*)Ql + qb + (long)r*128 + off, (char*)&sKl[0][0] + L);
        }
    }
    __syncthreads();
    bf16x8 qa[2][2];
#pragma unroll
    for (int k0 = 0; k0 < 2; ++k0) {
        int o = (w*16 + lr) * 64 + ((k0*32 + ks*8) ^ (sxq << 3));
        qa[k0][0] = *(const bf16x8*)&sKh[0][o];
        qa[k0][1] = *(const bf16x8*)&sKl[0][o];
    }
    __syncthreads();

    auto stageK = [&](int buf, int kt) {
        const long kb = ((long)bh * SEQ + kt*64) * 128;
#pragma unroll
        for (int i2 = 0; i2 < 4; ++i2) {
            int L = i2*2048 + t*16; int r = L >> 7, off = L & 127;
            gld16((const char*)Kh + kb + (long)r*128 + off, (char*)&sKh[buf][0] + L);
            gld16((const char*)Kl + kb + (long)r*128 + off, (char*)&sKl[buf][0] + L);
        }
    };
    auto stageV = [&](int buf, int kt) {
        const long vb = ((long)bh * 64) * 2048 + (long)kt * 128;
#pragma unroll
        for (int i2 = 0; i2 < 4; ++i2) {
            int L = i2*2048 + t*16; int r = L >> 7, off = L & 127;
            gld16((const char*)VTh + vb + (long)r*2048 + off, (char*)&sVh[buf][0] + L);
        }
    };
    auto scoresOf = [&](int buf, int kt, f32x4* sc) {
#pragma unroll
        for (int nt = 0; nt < 4; ++nt) sc[nt] = (f32x4){0.f, 0.f, 0.f, 0.f};
#pragma unroll
        for (int k0 = 0; k0 < 2; ++k0) {
            bf16x8 kh[4], kl[4];
#pragma unroll
            for (int nt = 0; nt < 4; ++nt) {
                int o = (nt*16 + lr) * 64 + ((k0*32 + ks*8) ^ (sxq << 3));
                kh[nt] = *(const bf16x8*)&sKh[buf][o];
                kl[nt] = *(const bf16x8*)&sKl[buf][o];
            }
#pragma unroll
            for (int nt = 0; nt < 4; ++nt) {
                sc[nt] = __builtin_amdgcn_mfma_f32_16x16x32_bf16(
                    qa[k0][0], kh[nt], sc[nt], 0, 0, 0);
                sc[nt] = __builtin_amdgcn_mfma_f32_16x16x32_bf16(
                    qa[k0][0], kl[nt], sc[nt], 0, 0, 0);
                sc[nt] = __builtin_amdgcn_mfma_f32_16x16x32_bf16(
                    qa[k0][1], kh[nt], sc[nt], 0, 0, 0);
            }
        }
        if (CAUSAL && kt == diag) {
            int row = q0 + w*16 + rq*4;
#pragma unroll
            for (int nt = 0; nt < 4; ++nt) {
                int col = kt*64 + nt*16 + cq;
#pragma unroll
                for (int i = 0; i < 4; ++i)
                    if (col > row + i) sc[nt][i] = -1e9f;
            }
        }
    };

    // ---- pass 1: online max + sum ----
    float m[4]   = {-3e38f, -3e38f, -3e38f, -3e38f};
    float sum[4] = {0.f, 0.f, 0.f, 0.f};
    int cur = 0;
    stageK(0, 0);
    __syncthreads();
    for (int kt = 0; kt < ktmax; ++kt) {
        if (kt + 1 < ktmax) stageK(cur ^ 1, kt + 1);
        f32x4 sc[4];
        scoresOf(cur, kt, sc);
#pragma unroll
        for (int i = 0; i < 4; ++i) {
            float tm = fmaxf(fmaxf(sc[0][i], sc[1][i]), fmaxf(sc[2][i], sc[3][i]));
#pragma unroll
            for (int d2 = 1; d2 <= 8; d2 <<= 1) tm = fmaxf(tm, __shfl_xor(tm, d2, 64));
            float mn = fmaxf(m[i], tm);
            float ps = __expf(sc[0][i] - mn) + __expf(sc[1][i] - mn)
                     + __expf(sc[2][i] - mn) + __expf(sc[3][i] - mn);
#pragma unroll
            for (int d2 = 1; d2 <= 8; d2 <<= 1) ps += __shfl_xor(ps, d2, 64);
            sum[i] = sum[i] * __expf(m[i] - mn) + ps;
            m[i] = mn;
        }
        __syncthreads();
        cur ^= 1;
    }
    float inv[4];
#pragma unroll
    for (int i = 0; i < 4; ++i) inv[i] = 1.f / sum[i];

    // ---- pass 2: recompute, probs out, PV (1-product) ----
    f32x4 acco[4];
#pragma unroll
    for (int nt = 0; nt < 4; ++nt) acco[nt] = (f32x4){0.f, 0.f, 0.f, 0.f};

    cur = 0;
    stageK(0, 0); stageV(0, 0);
    __syncthreads();
    for (int kt = 0; kt < 16; ++kt) {
        if (kt >= ktmax) {
#pragma unroll
            for (int nt = 0; nt < 4; ++nt)
#pragma unroll
                for (int i = 0; i < 4; ++i)
                    attn[((long)bh << 20) + ((long)(q0 + w*16 + rq*4 + i) << 10)
                         + kt*64 + nt*16 + cq] = 0.f;
            continue;
        }
        if (kt + 1 < ktmax) { stageK(cur ^ 1, kt + 1); stageV(cur ^ 1, kt + 1); }
        f32x4 sc[4];
        scoresOf(cur, kt, sc);
#pragma unroll
        for (int nt = 0; nt < 4; ++nt)
#pragma unroll
            for (int i = 0; i < 4; ++i) {
                float p = __expf(sc[nt][i] - m[i]) * inv[i];
                attn[((long)bh << 20) + ((long)(q0 + w*16 + rq*4 + i) << 10)
                     + kt*64 + nt*16 + cq] = p;
                sPh[w][(rq*4 + i)*80 + nt*16 + cq] = f2bf(p);
            }
#pragma unroll
        for (int k0 = 0; k0 < 2; ++k0) {
            bf16x8 pah = *(const bf16x8*)&sPh[w][lr*80 + k0*32 + ks*8];
#pragma unroll
            for (int nt = 0; nt < 4; ++nt) {
                int dk = nt*16 + lr;
                int swz = (((dk >> 1) & 3) << 3) | (((dk >> 3) & 1) << 5);
                int koff = (k0*32 + ks*8) ^ swz;
                bf16x8 vh8 = *(const bf16x8*)&sVh[cur][dk*64 + koff];
                acco[nt] = __builtin_amdgcn_mfma_f32_16x16x32_bf16(
                    pah, vh8, acco[nt], 0, 0, 0);
            }
        }
        __syncthreads();
        cur ^= 1;
    }

    const int b = bh >> 3, hh_ = bh & 7;
#pragma unroll
    for (int nt = 0; nt < 4; ++nt)
#pragma unroll
        for (int i = 0; i < 4; ++i) {
            long oidx = ((long)(b * SEQ + q0 + w*16 + rq*4 + i)) * D_MODEL
                      + hh_*64 + nt*16 + cq;
            Oh[oidx] = f2bf(acco[nt][i]);
        }
}

// ---------------- residual + NS partial slabs + bias + LayerNorm + hi -------
template<int NS>
__global__ __launch_bounds__(256) void add_ln_kernel(
    const float* __restrict__ xin, const float* __restrict__ part, long PS,
    const float* __restrict__ bias,
    const float* __restrict__ g, const float* __restrict__ bb,
    float* __restrict__ xout, short* __restrict__ xh)
{
    long row = blockIdx.x;
    const float* xr = xin + row * D_MODEL;
    float*       xo = xout+ row * D_MODEL;
    short*       hh = xh  + row * D_MODEL;
    int t = threadIdx.x;

    float a0 = xr[t]       + bias[t];
    float a1 = xr[t + 256] + bias[t + 256];
#pragma unroll
    for (int s2 = 0; s2 < NS; ++s2) {
        a0 += part[s2 * PS + row * D_MODEL + t];
        a1 += part[s2 * PS + row * D_MODEL + t + 256];
    }

    float s = a0 + a1;
#pragma unroll
    for (int m = 32; m; m >>= 1) s += __shfl_xor(s, m, 64);
    __shared__ float red1[4];
    __shared__ float red2[4];
    int w = t >> 6, lane = t & 63;
    if (lane == 0) red1[w] = s;
    __syncthreads();
    float mean = (red1[0] + red1[1] + red1[2] + red1[3]) * (1.f / 512.f);

    float d0 = a0 - mean, d1 = a1 - mean;
    float q = d0 * d0 + d1 * d1;
#pragma unroll
    for (int m = 32; m; m >>= 1) q += __shfl_xor(q, m, 64);
    if (lane == 0) red2[w] = q;
    __syncthreads();
    float var  = (red2[0] + red2[1] + red2[2] + red2[3]) * (1.f / 512.f);
    float rstd = rsqrtf(var + 1e-5f);

    float r0 = d0 * rstd * g[t]       + bb[t];
    float r1 = d1 * rstd * g[t + 256] + bb[t + 256];
    xo[t] = r0; xo[t + 256] = r1;
    hh[t] = f2bf(r0);
    hh[t + 256] = f2bf(r1);
}

// ---------------------------------------------------------------------------
extern "C" void kernel_launch(void* const* d_in, const int* in_sizes, int n_in,
                              void* d_out, int out_size, void* d_ws, size_t ws_size,
                              hipStream_t stream)
{
    const int*   tokens = (const int*)  d_in[0];
    const float* enc    = (const float*)d_in[1];
    const float* emb    = (const float*)d_in[3];
    const float* Wqkvo  = (const float*)d_in[4];   // [L,2,4,D,D]
    const float* bqkvo  = (const float*)d_in[5];   // [L,2,4,D]
    const float* W1     = (const float*)d_in[6];   // [L,D,DFF]
    const float* b1     = (const float*)d_in[7];
    const float* W2     = (const float*)d_in[8];   // [L,DFF,D]
    const float* b2     = (const float*)d_in[9];
    const float* lng    = (const float*)d_in[10];  // [L,3,D]
    const float* lnb    = (const float*)d_in[11];
    const float* Wout   = (const float*)d_in[12];  // [D,V]
    const float* bout   = (const float*)d_in[13];

    float* out    = (float*)d_out;
    float* selfA  = out + 65536000L;
    float* crossA = selfA + 67108864L;

    // workspace carve
    char* p = (char*)d_ws;
    auto carve = [&](size_t bytes) { char* r = p; p += (bytes + 255) & ~255UL; return r; };
    float* x      = (float*)carve(1048576L * 4);
    short* xh     = (short*)carve(1048576L * 2);
    short* ench   = (short*)carve(1048576L * 2);
    short* qh     = (short*)carve(2097152L * 2);   // head-major Q|K hi
    short* ql     = (short*)carve(2097152L * 2);   // head-major Q|K lo
    short* vth    = (short*)carve(1048576L * 2);   // transposed V hi
    short* oh     = (short*)carve(1048576L * 2);
    short* t1h    = (short*)carve(4194304L * 2);   // FFN1 out hi
    float* part   = (float*)carve(4L * PSLAB * 4); // 4 K-split slabs
    short* WTLh   = (short*)carve(4194304L * 2);   // per-layer weights T hi
    short* WTh    = (short*)carve(8192000L * 2);   // vocab chunk T hi

    const long PW = 262144L;    // 512*512
    const long HS = 1048576L;   // per attention operand slab

    embed_pe_kernel<<<4096, 256, 0, stream>>>(tokens, emb, x, xh);
    cvt_kernel<<<1024, 256, 0, stream>>>(enc, ench);

    for (int l = 0; l < NLAYER; ++l) {
        const float* bl = bqkvo + (long)l * 4096L;
        const float* bc = bl + 2048;
        const float* g  = lng + (long)l * 3 * 512;
        const float* bb = lnb + (long)l * 3 * 512;

        wtrans_layer_kernel<<<1024, 256, 0, stream>>>(Wqkvo, W1, W2, l, WTLh);

        // ---- self-attention (QKV one dispatch, A always xh) ----
        gemm_mfma_kernel<64,64,0,3,true><<<dim3(8, 32, 3), 256, 0, stream>>>(
            xh, xh, WTLh, bl, nullptr, qh, ql, vth,
            512, 512, 512, 0, PW, 512, HS, 0, /*scaledZ=*/0, /*vtZ=*/2,
            /*aSwitchZ=*/3);
        attn_fused_kernel<true><<<dim3(32, 16), 128, 0, stream>>>(
            qh, ql, qh + HS, ql + HS, vth,
            selfA + (long)l * 16777216L, oh);
        gemm_mfma_kernel<64,64,0,5,true><<<dim3(8, 32, 2), 256, 0, stream>>>(
            oh, nullptr, WTLh + 3*PW, nullptr, part, nullptr, nullptr, nullptr,
            256, 512, 512, 512, 0, 0, PSLAB, 256, -1, -1, 99);
        add_ln_kernel<2><<<MROWS, 256, 0, stream>>>(
            x, part, PSLAB, bl + 3*512, g, bb, x, xh);

        // ---- cross-attention (QKV merged: z0 Q from xh, z1 K / z2 V from enc)
        gemm_mfma_kernel<64,64,0,3,true><<<dim3(8, 32, 3), 256, 0, stream>>>(
            xh, ench, WTLh + 4*PW, bc, nullptr, qh, ql, vth,
            512, 512, 512, 0, PW, 512, HS, 0, /*scaledZ=*/0, /*vtZ=*/2,
            /*aSwitchZ=*/1);
        attn_fused_kernel<false><<<dim3(32, 16), 128, 0, stream>>>(
            qh, ql, qh + HS, ql + HS, vth,
            crossA + (long)l * 16777216L, oh);
        gemm_mfma_kernel<64,64,0,5,true><<<dim3(8, 32, 2), 256, 0, stream>>>(
            oh, nullptr, WTLh + 7*PW, nullptr, part, nullptr, nullptr, nullptr,
            256, 512, 512, 512, 0, 0, PSLAB, 256, -1, -1, 99);
        add_ln_kernel<2><<<MROWS, 256, 0, stream>>>(
            x, part, PSLAB, bc + 3*512, g + 512, bb + 512, x, xh);

        // ---- FFN ----
        gemm_mfma_kernel<64,64,1,2,true><<<dim3(32, 32, 1), 256, 0, stream>>>(
            xh, nullptr, WTLh + 2097152L, b1 + (long)l * 2048,
            nullptr, t1h, nullptr, nullptr,
            512, 512, 512, 2048, 0, 0, 0, 0, -1, -1, 99);
        gemm_mfma_kernel<64,64,0,5,true><<<dim3(8, 32, 4), 256, 0, stream>>>(
            t1h, nullptr, WTLh + 3145728L, nullptr, part,
            nullptr, nullptr, nullptr,
            512, 2048, 2048, 512, 0, 0, PSLAB, 512, -1, -1, 99);
        add_ln_kernel<4><<<MROWS, 256, 0, stream>>>(
            x, part, PSLAB, b2 + (long)l * 512, g + 1024, bb + 1024, x, xh);
    }

    // ---- final vocab projection, two 16000-wide chunks ----
    for (int c = 0; c < 2; ++c) {
        wtrans_kernel<<<dim3(250, 8, 1), 256, 0, stream>>>(
            Wout + c * 16000, WTh, 512, VOCAB);
        gemm_mfma_kernel<128,128,0,0,true><<<dim3(125, 16, 1), 256, 0, stream>>>(
            xh, nullptr, WTh, bout + c * 16000, out + c * 16000,
            nullptr, nullptr, nullptr,
            512, 512, 512, VOCAB, 0, 0, 0, 0, -1, -1, 99);
    }
}